// Round 2
// baseline (491.345 us; speedup 1.0000x reference)
//
#include <hip/hip_runtime.h>
#include <hip/hip_bf16.h>

#define BB 4
#define NN 4096
#define MM 4096
#define CC 256
#define CAP 128
#define NBIN 384

typedef __attribute__((ext_vector_type(8))) short bf16x8;
typedef __attribute__((ext_vector_type(4))) float f32x4;

static __device__ __forceinline__ float bf2f(unsigned short u) {
    return __uint_as_float(((unsigned)u) << 16);
}
static __device__ __forceinline__ unsigned short f2bf(float f) {
    unsigned u = __float_as_uint(f);
    u += 0x7fffu + ((u >> 16) & 1u);   // round-to-nearest-even
    return (unsigned short)(u >> 16);
}

// ---------------- W fp32 -> bf16 (all four matrices) ----------------
__global__ void wprep_kernel(const float* __restrict__ Wq, const float* __restrict__ Wk,
                             const float* __restrict__ Wv, const float* __restrict__ Wm,
                             unsigned short* __restrict__ Wbf) {
    int i = blockIdx.x * 256 + threadIdx.x;
    Wbf[i]          = f2bf(Wq[i]);
    Wbf[65536 + i]  = f2bf(Wk[i]);
    Wbf[131072 + i] = f2bf(Wv[i]);
    Wbf[196608 + i] = f2bf(Wm[i]);
}

// ---------------- MFMA projection: O = A @ W^T + b ----------------
// A [16384][256] (fp32 or bf16), W bf16 [256][256] row-major ([out][in] == B^T),
// 128 rows per block, 4 waves x 32 rows, N=256 (16 n-tiles), K=256 (8 k-steps).
template <bool IN_BF16, bool OUT_BF16, bool DO_VSUM>
__global__ __launch_bounds__(256, 2) void proj_mfma_kernel(
    const void* __restrict__ Ain, const unsigned short* __restrict__ Wbf,
    const float* __restrict__ bias, void* __restrict__ Out, float* __restrict__ Vsum)
{
    __shared__ unsigned short As[128 * 256];   // 64 KB, XOR-swizzled (16B granule)
    const int tid = threadIdx.x;
    const size_t r0 = (size_t)blockIdx.x * 128;

    if constexpr (!IN_BF16) {
        const float* A = (const float*)Ain + r0 * CC;
#pragma unroll
        for (int it = 0; it < 16; ++it) {
            int idx = it * 2048 + tid * 8;
            float4 f0 = *(const float4*)(A + idx);
            float4 f1 = *(const float4*)(A + idx + 4);
            int row = idx >> 8, col = idx & 255;
            int off = row * 512 + ((col * 2) ^ ((row & 7) << 4));
            ushort4* dst = (ushort4*)((char*)As + off);
            dst[0] = make_ushort4(f2bf(f0.x), f2bf(f0.y), f2bf(f0.z), f2bf(f0.w));
            dst[1] = make_ushort4(f2bf(f1.x), f2bf(f1.y), f2bf(f1.z), f2bf(f1.w));
        }
    } else {
        const unsigned short* A = (const unsigned short*)Ain + r0 * CC;
#pragma unroll
        for (int it = 0; it < 16; ++it) {
            int idx = it * 2048 + tid * 8;
            uint4 d = *(const uint4*)(A + idx);
            int row = idx >> 8, col = idx & 255;
            int off = row * 512 + ((col * 2) ^ ((row & 7) << 4));
            *(uint4*)((char*)As + off) = d;
        }
    }
    __syncthreads();

    const int wid = tid >> 6, lane = tid & 63;
    const int lrow = lane & 15, lk = lane >> 4;
    const int xr = (lrow & 7) << 4;

    f32x4 acc[16][2];
#pragma unroll
    for (int t = 0; t < 16; ++t) {
        acc[t][0] = (f32x4){0.f, 0.f, 0.f, 0.f};
        acc[t][1] = (f32x4){0.f, 0.f, 0.f, 0.f};
    }

    const char* asb = (const char*)As;
#pragma unroll
    for (int kk = 0; kk < 8; ++kk) {
        int kbyte = kk * 64 + lk * 16;
        int r0l = wid * 32 + lrow;
        bf16x8 a0 = *(const bf16x8*)(asb + r0l * 512 + (kbyte ^ xr));
        bf16x8 a1 = *(const bf16x8*)(asb + (r0l + 16) * 512 + (kbyte ^ xr));
        const unsigned short* wp = Wbf + (size_t)lrow * CC + kk * 32 + lk * 8;
#pragma unroll
        for (int t = 0; t < 16; ++t) {
            bf16x8 bfrag = *(const bf16x8*)(wp + (size_t)t * 16 * CC);
            acc[t][0] = __builtin_amdgcn_mfma_f32_16x16x32_bf16(a0, bfrag, acc[t][0], 0, 0, 0);
            acc[t][1] = __builtin_amdgcn_mfma_f32_16x16x32_bf16(a1, bfrag, acc[t][1], 0, 0, 0);
        }
    }

#pragma unroll
    for (int t = 0; t < 16; ++t) {
        int col = t * 16 + lrow;
        float bb = bias[col];
        float vs = 0.f;
#pragma unroll
        for (int T = 0; T < 2; ++T) {
#pragma unroll
            for (int rr = 0; rr < 4; ++rr) {
                int row = wid * 32 + T * 16 + lk * 4 + rr;
                float val = acc[t][T][rr] + bb;
                if constexpr (OUT_BF16)
                    ((unsigned short*)Out)[(r0 + row) * CC + col] = f2bf(val);
                else
                    ((float*)Out)[(r0 + row) * CC + col] = val;
                if constexpr (DO_VSUM) vs += acc[t][T][rr];
            }
        }
        if constexpr (DO_VSUM) {
            vs += __shfl_xor(vs, 16);
            vs += __shfl_xor(vs, 32);
            if (lk == 0) atomicAdd(&Vsum[(blockIdx.x >> 5) * CC + col], vs + 32.f * bb);
        }
    }
}

// ---------------- deterministic v-binning of R keypoints ----------------
// one block per batch, 768 threads = (bin v, half h); two-pass count+fill.
__global__ __launch_bounds__(768) void bin_kernel(const float* __restrict__ kptsR,
        int* __restrict__ binStart, unsigned short* __restrict__ sortedM,
        float2* __restrict__ sortedUV)
{
    __shared__ int cnt2[768];
    __shared__ int sc[NBIN];
    int tid = threadIdx.x, b = blockIdx.x;
    int h = tid / NBIN, v = tid - h * NBIN;
    const float2* kp = (const float2*)(kptsR + (size_t)b * MM * 2);
    int c = 0;
    for (int m = h * 2048; m < h * 2048 + 2048; ++m) {
        float vr = kp[m].y;
        c += ((int)vr == v);
    }
    cnt2[tid] = c;
    __syncthreads();
    if (tid < NBIN) sc[tid] = cnt2[tid] + cnt2[NBIN + tid];
    __syncthreads();
    for (int off = 1; off < NBIN; off <<= 1) {
        int t = (tid < NBIN && tid >= off) ? sc[tid - off] : 0;
        __syncthreads();
        if (tid < NBIN) sc[tid] += t;
        __syncthreads();
    }
    if (tid < NBIN) binStart[b * (NBIN + 1) + tid] = (tid ? sc[tid - 1] : 0);
    if (tid == 0) binStart[b * (NBIN + 1) + NBIN] = sc[NBIN - 1];
    int off = (v ? sc[v - 1] : 0) + (h ? cnt2[v] : 0);
    for (int m = h * 2048; m < h * 2048 + 2048; ++m) {
        float2 p = kp[m];
        if ((int)p.y == v) {
            sortedM[(b << 12) + off] = (unsigned short)m;
            sortedUV[(b << 12) + off] = p;
            ++off;
        }
    }
}

// ---------------- mean of u_R per batch ----------------
__global__ __launch_bounds__(256) void urmean_kernel(const float* __restrict__ kptsR,
                                                     float* __restrict__ Usum) {
    int b = blockIdx.x;
    int tid = threadIdx.x;
    float s = 0.f;
    for (int m = tid; m < MM; m += 256) s += kptsR[((size_t)b * MM + m) * 2 + 0];
#pragma unroll
    for (int off = 32; off; off >>= 1) s += __shfl_xor(s, off);
    __shared__ float sr[4];
    int wave = tid >> 6, lane = tid & 63;
    if (lane == 0) sr[wave] = s;
    __syncthreads();
    if (tid == 0) Usum[b] = sr[0] + sr[1] + sr[2] + sr[3];
}

// ---------------- sparse attention: one wave per query row ----------------
__global__ __launch_bounds__(256) void attn_kernel(
    const unsigned short* __restrict__ Q, const unsigned short* __restrict__ K,
    const unsigned short* __restrict__ V,
    const float* __restrict__ kptsL,
    const int* __restrict__ binStart, const unsigned short* __restrict__ sortedM,
    const float2* __restrict__ sortedUV,
    const float* __restrict__ Vsum, const float* __restrict__ Usum,
    unsigned short* __restrict__ MT, float* __restrict__ out1, float* __restrict__ out2)
{
    __shared__ unsigned short s_m[4][CAP];
    __shared__ float s_du[4][CAP];
    __shared__ float s_p[4][CAP];

    const int wid = threadIdx.x >> 6, lane = threadIdx.x & 63;
    const int bn = blockIdx.x * 4 + wid;
    const int b = bn >> 12;

    float2 kl = *(const float2*)(kptsL + (size_t)bn * 2);
    float uL = kl.x, vL = kl.y;

    int ifl = (int)vL;
    int v0 = max(0, ifl - 3), v1 = min(NBIN - 1, ifl + 3);
    int s = binStart[b * (NBIN + 1) + v0];
    int e = binStart[b * (NBIN + 1) + v1 + 1];

    // ballot-compact valid candidates from the contiguous v-window slice
    int cnt = 0;
    for (int i0 = s; i0 < e; i0 += 64) {
        int i = i0 + lane;
        bool valid = false;
        float du = 0.f;
        int m = 0;
        if (i < e) {
            float2 uv = sortedUV[(b << 12) + i];
            m = sortedM[(b << 12) + i];
            du = uL - uv.x;
            float dv = fabsf(vL - uv.y);
            valid = (dv < 3.0f) && (du > 0.0f) && (du < 192.0f);
        }
        unsigned long long bal = __ballot(valid);
        int pos = cnt + __popcll(bal & ((1ull << lane) - 1ull));
        if (valid && pos < CAP) { s_m[wid][pos] = (unsigned short)m; s_du[wid][pos] = du; }
        cnt += __popcll(bal);
    }
    if (cnt > CAP) cnt = CAP;

    if (cnt == 0) {
        // all-masked row: softmax over 4096 equal logits -> uniform 1/M
        float4 vs = *(const float4*)(Vsum + b * CC + lane * 4);
        ushort4 o = make_ushort4(f2bf(vs.x * (1.f / MM)), f2bf(vs.y * (1.f / MM)),
                                 f2bf(vs.z * (1.f / MM)), f2bf(vs.w * (1.f / MM)));
        *(ushort4*)(MT + (size_t)bn * CC + lane * 4) = o;
        if (lane == 0) { out1[bn] = uL - Usum[b] * (1.f / MM); out2[bn] = 0.f; }
        return;
    }

    // logits: wave-wide 256-dim dot per candidate
    ushort4 qu = *(const ushort4*)(Q + (size_t)bn * CC + lane * 4);
    float q0 = bf2f(qu.x), q1 = bf2f(qu.y), q2 = bf2f(qu.z), q3 = bf2f(qu.w);
    const unsigned short* Kb = K + (((size_t)b) << 12) * CC;
    for (int i = 0; i < cnt; ++i) {
        ushort4 kv = *(const ushort4*)(Kb + (size_t)s_m[wid][i] * CC + lane * 4);
        float d = q0 * bf2f(kv.x) + q1 * bf2f(kv.y) + q2 * bf2f(kv.z) + q3 * bf2f(kv.w);
#pragma unroll
        for (int off = 32; off; off >>= 1) d += __shfl_xor(d, off);
        if (lane == 0) s_p[wid][i] = d;
    }

    // softmax over the valid set (masked entries underflow to exactly 0 in ref)
    const float NEG = -3.0e38f;
    float x0 = (lane < cnt) ? s_p[wid][lane] * 0.0625f : NEG;
    float x1 = (lane + 64 < cnt) ? s_p[wid][lane + 64] * 0.0625f : NEG;
    float mx = fmaxf(x0, x1);
#pragma unroll
    for (int off = 32; off; off >>= 1) mx = fmaxf(mx, __shfl_xor(mx, off));
    float p0 = (lane < cnt) ? expf(x0 - mx) : 0.f;
    float p1 = (lane + 64 < cnt) ? expf(x1 - mx) : 0.f;
    float d0 = (lane < cnt) ? s_du[wid][lane] : 0.f;
    float d1 = (lane + 64 < cnt) ? s_du[wid][lane + 64] : 0.f;
    float ps = p0 + p1, ds = p0 * d0 + p1 * d1;
#pragma unroll
    for (int off = 32; off; off >>= 1) { ps += __shfl_xor(ps, off); ds += __shfl_xor(ds, off); }
    float inv = 1.f / ps;
    if (lane < cnt) s_p[wid][lane] = p0 * inv;
    if (lane + 64 < cnt) s_p[wid][lane + 64] = p1 * inv;

    // PV: lane owns 4 output channels
    const unsigned short* Vb = V + (((size_t)b) << 12) * CC;
    float a0 = 0.f, a1 = 0.f, a2 = 0.f, a3 = 0.f;
    for (int i = 0; i < cnt; ++i) {
        float w = s_p[wid][i];
        ushort4 vv = *(const ushort4*)(Vb + (size_t)s_m[wid][i] * CC + lane * 4);
        a0 += w * bf2f(vv.x); a1 += w * bf2f(vv.y);
        a2 += w * bf2f(vv.z); a3 += w * bf2f(vv.w);
    }
    ushort4 o = make_ushort4(f2bf(a0), f2bf(a1), f2bf(a2), f2bf(a3));
    *(ushort4*)(MT + (size_t)bn * CC + lane * 4) = o;
    if (lane == 0) { out1[bn] = ds * inv; out2[bn] = 1.f; }
}

extern "C" void kernel_launch(void* const* d_in, const int* in_sizes, int n_in,
                              void* d_out, int out_size, void* d_ws, size_t ws_size,
                              hipStream_t stream) {
    const float* nodes_L = (const float*)d_in[0];
    const float* nodes_R = (const float*)d_in[1];
    const float* kpts_L  = (const float*)d_in[2];
    const float* kpts_R  = (const float*)d_in[3];
    const float* Wq = (const float*)d_in[4];
    const float* bq = (const float*)d_in[5];
    const float* Wk = (const float*)d_in[6];
    const float* bk = (const float*)d_in[7];
    const float* Wv = (const float*)d_in[8];
    const float* bv = (const float*)d_in[9];
    const float* Wm = (const float*)d_in[10];
    const float* bm = (const float*)d_in[11];

    char* ws = (char*)d_ws;
    unsigned short* Wbf = (unsigned short*)ws; ws += (size_t)4 * 65536 * 2;
    unsigned short* Qp  = (unsigned short*)ws; ws += (size_t)BB * NN * CC * 2;
    unsigned short* Kp  = (unsigned short*)ws; ws += (size_t)BB * MM * CC * 2;
    unsigned short* Vp  = (unsigned short*)ws; ws += (size_t)BB * MM * CC * 2;
    unsigned short* MT  = (unsigned short*)ws; ws += (size_t)BB * NN * CC * 2;
    float* Vsum = (float*)ws;        ws += (size_t)BB * CC * 4;
    float* Usum = (float*)ws;        ws += (size_t)BB * 4;
    float2* sortedUV = (float2*)ws;  ws += (size_t)BB * MM * 8;
    int* binStart = (int*)ws;        ws += (size_t)BB * (NBIN + 1) * 4;
    unsigned short* sortedM = (unsigned short*)ws;

    float* out0 = (float*)d_out;
    float* out1 = out0 + (size_t)BB * NN * CC;
    float* out2 = out1 + (size_t)BB * NN;

    hipMemsetAsync(Vsum, 0, (size_t)BB * CC * sizeof(float), stream);

    wprep_kernel<<<dim3(256), dim3(256), 0, stream>>>(Wq, Wk, Wv, Wm, Wbf);

    proj_mfma_kernel<false, true, false><<<dim3(128), dim3(256), 0, stream>>>(
        nodes_L, Wbf, bq, Qp, nullptr);
    proj_mfma_kernel<false, true, false><<<dim3(128), dim3(256), 0, stream>>>(
        nodes_R, Wbf + 65536, bk, Kp, nullptr);
    proj_mfma_kernel<false, true, true><<<dim3(128), dim3(256), 0, stream>>>(
        nodes_R, Wbf + 131072, bv, Vp, Vsum);

    bin_kernel<<<dim3(BB), dim3(768), 0, stream>>>(kpts_R, binStart, sortedM, sortedUV);
    urmean_kernel<<<dim3(BB), dim3(256), 0, stream>>>(kpts_R, Usum);

    attn_kernel<<<dim3(BB * NN / 4), dim3(256), 0, stream>>>(
        Qp, Kp, Vp, kpts_L, binStart, sortedM, sortedUV, Vsum, Usum, MT, out1, out2);

    proj_mfma_kernel<true, false, false><<<dim3(128), dim3(256), 0, stream>>>(
        MT, Wbf + 196608, bm, out0, nullptr);
}

// Round 3
// 160.460 us; speedup vs baseline: 3.0621x; 3.0621x over previous
//
#include <hip/hip_runtime.h>
#include <hip/hip_bf16.h>

#define BB 4
#define NN 4096
#define MM 4096
#define CC 256
#define CAP 128
#define NBIN 384
#define NCH 16
#define CHK 256

typedef __attribute__((ext_vector_type(8))) short bf16x8;
typedef __attribute__((ext_vector_type(4))) float f32x4;

static __device__ __forceinline__ float bf2f(unsigned short u) {
    return __uint_as_float(((unsigned)u) << 16);
}
static __device__ __forceinline__ unsigned short f2bf(float f) {
    unsigned u = __float_as_uint(f);
    u += 0x7fffu + ((u >> 16) & 1u);   // round-to-nearest-even
    return (unsigned short)(u >> 16);
}

// ---------------- W fp32 -> bf16 (all four matrices) ----------------
__global__ void wprep_kernel(const float* __restrict__ Wq, const float* __restrict__ Wk,
                             const float* __restrict__ Wv, const float* __restrict__ Wm,
                             unsigned short* __restrict__ Wbf) {
    int i = blockIdx.x * 256 + threadIdx.x;
    Wbf[i]          = f2bf(Wq[i]);
    Wbf[65536 + i]  = f2bf(Wk[i]);
    Wbf[131072 + i] = f2bf(Wv[i]);
    Wbf[196608 + i] = f2bf(Wm[i]);
}

// ---------------- MFMA projection: O = A @ W^T + b ----------------
template <bool IN_BF16, bool OUT_BF16, bool DO_VSUM>
__global__ __launch_bounds__(256, 2) void proj_mfma_kernel(
    const void* __restrict__ Ain, const unsigned short* __restrict__ Wbf,
    const float* __restrict__ bias, void* __restrict__ Out, float* __restrict__ Vsum)
{
    __shared__ unsigned short As[128 * 256];   // 64 KB, XOR-swizzled (16B granule)
    const int tid = threadIdx.x;
    const size_t r0 = (size_t)blockIdx.x * 128;

    if constexpr (!IN_BF16) {
        const float* A = (const float*)Ain + r0 * CC;
#pragma unroll
        for (int it = 0; it < 16; ++it) {
            int idx = it * 2048 + tid * 8;
            float4 f0 = *(const float4*)(A + idx);
            float4 f1 = *(const float4*)(A + idx + 4);
            int row = idx >> 8, col = idx & 255;
            int off = row * 512 + ((col * 2) ^ ((row & 7) << 4));
            ushort4* dst = (ushort4*)((char*)As + off);
            dst[0] = make_ushort4(f2bf(f0.x), f2bf(f0.y), f2bf(f0.z), f2bf(f0.w));
            dst[1] = make_ushort4(f2bf(f1.x), f2bf(f1.y), f2bf(f1.z), f2bf(f1.w));
        }
    } else {
        const unsigned short* A = (const unsigned short*)Ain + r0 * CC;
#pragma unroll
        for (int it = 0; it < 16; ++it) {
            int idx = it * 2048 + tid * 8;
            uint4 d = *(const uint4*)(A + idx);
            int row = idx >> 8, col = idx & 255;
            int off = row * 512 + ((col * 2) ^ ((row & 7) << 4));
            *(uint4*)((char*)As + off) = d;
        }
    }
    __syncthreads();

    const int wid = tid >> 6, lane = tid & 63;
    const int lrow = lane & 15, lk = lane >> 4;
    const int xr = (lrow & 7) << 4;

    f32x4 acc[16][2];
#pragma unroll
    for (int t = 0; t < 16; ++t) {
        acc[t][0] = (f32x4){0.f, 0.f, 0.f, 0.f};
        acc[t][1] = (f32x4){0.f, 0.f, 0.f, 0.f};
    }

    const char* asb = (const char*)As;
#pragma unroll
    for (int kk = 0; kk < 8; ++kk) {
        int kbyte = kk * 64 + lk * 16;
        int r0l = wid * 32 + lrow;
        bf16x8 a0 = *(const bf16x8*)(asb + r0l * 512 + (kbyte ^ xr));
        bf16x8 a1 = *(const bf16x8*)(asb + (r0l + 16) * 512 + (kbyte ^ xr));
        const unsigned short* wp = Wbf + (size_t)lrow * CC + kk * 32 + lk * 8;
#pragma unroll
        for (int t = 0; t < 16; ++t) {
            bf16x8 bfrag = *(const bf16x8*)(wp + (size_t)t * 16 * CC);
            acc[t][0] = __builtin_amdgcn_mfma_f32_16x16x32_bf16(a0, bfrag, acc[t][0], 0, 0, 0);
            acc[t][1] = __builtin_amdgcn_mfma_f32_16x16x32_bf16(a1, bfrag, acc[t][1], 0, 0, 0);
        }
    }

#pragma unroll
    for (int t = 0; t < 16; ++t) {
        int col = t * 16 + lrow;
        float bb = bias[col];
        float vs = 0.f;
#pragma unroll
        for (int T = 0; T < 2; ++T) {
#pragma unroll
            for (int rr = 0; rr < 4; ++rr) {
                int row = wid * 32 + T * 16 + lk * 4 + rr;
                float val = acc[t][T][rr] + bb;
                if constexpr (OUT_BF16)
                    ((unsigned short*)Out)[(r0 + row) * CC + col] = f2bf(val);
                else
                    ((float*)Out)[(r0 + row) * CC + col] = val;
                if constexpr (DO_VSUM) vs += acc[t][T][rr];
            }
        }
        if constexpr (DO_VSUM) {
            vs += __shfl_xor(vs, 16);
            vs += __shfl_xor(vs, 32);
            if (lk == 0) atomicAdd(&Vsum[(blockIdx.x >> 5) * CC + col], vs + 32.f * bb);
        }
    }
}

// ---------------- deterministic chunked counting sort by v-bin ----------------
// phase 1: per-chunk histogram + stable within-chunk rank
__global__ __launch_bounds__(256) void bin_count_kernel(
    const float* __restrict__ kptsR, int* __restrict__ hist,
    unsigned short* __restrict__ prank)
{
    __shared__ int h[NBIN];
    __shared__ short sbin[CHK];
    int tid = threadIdx.x, chunk = blockIdx.x, b = blockIdx.y;
    for (int i = tid; i < NBIN; i += CHK) h[i] = 0;
    int m = chunk * CHK + tid;
    float2 p = ((const float2*)kptsR)[(size_t)b * MM + m];
    int bin = (int)p.y;
    sbin[tid] = (short)bin;
    __syncthreads();
    atomicAdd(&h[bin], 1);
    int r = 0;
    for (int t = 0; t < tid; ++t) r += (sbin[t] == bin);
    prank[(b << 12) + m] = (unsigned short)r;
    __syncthreads();
    for (int i = tid; i < NBIN; i += CHK)
        hist[((size_t)b * NCH + chunk) * NBIN + i] = h[i];
}

// phase 2: per-batch exclusive bin scan + per-(chunk,bin) offsets
__global__ __launch_bounds__(NBIN) void bin_scan_kernel(
    const int* __restrict__ hist, int* __restrict__ binStart, int* __restrict__ chunkOff)
{
    __shared__ int sc[NBIN];
    int b = blockIdx.x, v = threadIdx.x;
    int per[NCH];
    int tot = 0;
#pragma unroll
    for (int c = 0; c < NCH; ++c) { per[c] = hist[((size_t)b * NCH + c) * NBIN + v]; tot += per[c]; }
    sc[v] = tot;
    __syncthreads();
    for (int off = 1; off < NBIN; off <<= 1) {
        int t = (v >= off) ? sc[v - off] : 0;
        __syncthreads();
        sc[v] += t;
        __syncthreads();
    }
    int start = v ? sc[v - 1] : 0;
    binStart[b * (NBIN + 1) + v] = start;
    if (v == NBIN - 1) binStart[b * (NBIN + 1) + NBIN] = sc[NBIN - 1];
    int run = start;
#pragma unroll
    for (int c = 0; c < NCH; ++c) {
        chunkOff[((size_t)b * NCH + c) * NBIN + v] = run;
        run += per[c];
    }
}

// phase 3: scatter into (bin, m)-stable order
__global__ __launch_bounds__(256) void bin_place_kernel(
    const float* __restrict__ kptsR, const int* __restrict__ chunkOff,
    const unsigned short* __restrict__ prank,
    unsigned short* __restrict__ sortedM, float2* __restrict__ sortedUV)
{
    int tid = threadIdx.x, chunk = blockIdx.x, b = blockIdx.y;
    int m = chunk * CHK + tid;
    float2 p = ((const float2*)kptsR)[(size_t)b * MM + m];
    int bin = (int)p.y;
    int pos = chunkOff[((size_t)b * NCH + chunk) * NBIN + bin] + prank[(b << 12) + m];
    sortedM[(b << 12) + pos] = (unsigned short)m;
    sortedUV[(b << 12) + pos] = p;
}

// ---------------- mean of u_R per batch ----------------
__global__ __launch_bounds__(256) void urmean_kernel(const float* __restrict__ kptsR,
                                                     float* __restrict__ Usum) {
    int b = blockIdx.x;
    int tid = threadIdx.x;
    float s = 0.f;
    for (int m = tid; m < MM; m += 256) s += kptsR[((size_t)b * MM + m) * 2 + 0];
#pragma unroll
    for (int off = 32; off; off >>= 1) s += __shfl_xor(s, off);
    __shared__ float sr[4];
    int wave = tid >> 6, lane = tid & 63;
    if (lane == 0) sr[wave] = s;
    __syncthreads();
    if (tid == 0) Usum[b] = sr[0] + sr[1] + sr[2] + sr[3];
}

// ---------------- sparse attention: one wave per query row ----------------
__global__ __launch_bounds__(256) void attn_kernel(
    const unsigned short* __restrict__ Q, const unsigned short* __restrict__ K,
    const unsigned short* __restrict__ V,
    const float* __restrict__ kptsL,
    const int* __restrict__ binStart, const unsigned short* __restrict__ sortedM,
    const float2* __restrict__ sortedUV,
    const float* __restrict__ Vsum, const float* __restrict__ Usum,
    unsigned short* __restrict__ MT, float* __restrict__ out1, float* __restrict__ out2)
{
    __shared__ unsigned short s_m[4][CAP];
    __shared__ float s_du[4][CAP];
    __shared__ float s_p[4][CAP];

    const int wid = threadIdx.x >> 6, lane = threadIdx.x & 63;
    const int bn = blockIdx.x * 4 + wid;
    const int b = bn >> 12;

    float2 kl = *(const float2*)(kptsL + (size_t)bn * 2);
    float uL = kl.x, vL = kl.y;

    int ifl = (int)vL;
    int v0 = max(0, ifl - 3), v1 = min(NBIN - 1, ifl + 3);
    int s = binStart[b * (NBIN + 1) + v0];
    int e = binStart[b * (NBIN + 1) + v1 + 1];

    // ballot-compact valid candidates from the contiguous v-window slice
    int cnt = 0;
    for (int i0 = s; i0 < e; i0 += 64) {
        int i = i0 + lane;
        bool valid = false;
        float du = 0.f;
        int m = 0;
        if (i < e) {
            float2 uv = sortedUV[(b << 12) + i];
            m = sortedM[(b << 12) + i];
            du = uL - uv.x;
            float dv = fabsf(vL - uv.y);
            valid = (dv < 3.0f) && (du > 0.0f) && (du < 192.0f);
        }
        unsigned long long bal = __ballot(valid);
        int pos = cnt + __popcll(bal & ((1ull << lane) - 1ull));
        if (valid && pos < CAP) { s_m[wid][pos] = (unsigned short)m; s_du[wid][pos] = du; }
        cnt += __popcll(bal);
    }
    if (cnt > CAP) cnt = CAP;

    if (cnt == 0) {
        // all-masked row: softmax over 4096 equal logits -> uniform 1/M
        float4 vs = *(const float4*)(Vsum + b * CC + lane * 4);
        ushort4 o = make_ushort4(f2bf(vs.x * (1.f / MM)), f2bf(vs.y * (1.f / MM)),
                                 f2bf(vs.z * (1.f / MM)), f2bf(vs.w * (1.f / MM)));
        *(ushort4*)(MT + (size_t)bn * CC + lane * 4) = o;
        if (lane == 0) { out1[bn] = uL - Usum[b] * (1.f / MM); out2[bn] = 0.f; }
        return;
    }

    // logits: wave-wide 256-dim dot per candidate
    ushort4 qu = *(const ushort4*)(Q + (size_t)bn * CC + lane * 4);
    float q0 = bf2f(qu.x), q1 = bf2f(qu.y), q2 = bf2f(qu.z), q3 = bf2f(qu.w);
    const unsigned short* Kb = K + (((size_t)b) << 12) * CC;
    for (int i = 0; i < cnt; ++i) {
        ushort4 kv = *(const ushort4*)(Kb + (size_t)s_m[wid][i] * CC + lane * 4);
        float d = q0 * bf2f(kv.x) + q1 * bf2f(kv.y) + q2 * bf2f(kv.z) + q3 * bf2f(kv.w);
#pragma unroll
        for (int off = 32; off; off >>= 1) d += __shfl_xor(d, off);
        if (lane == 0) s_p[wid][i] = d;
    }

    // softmax over the valid set (masked entries underflow to exactly 0 in ref)
    const float NEG = -3.0e38f;
    float x0 = (lane < cnt) ? s_p[wid][lane] * 0.0625f : NEG;
    float x1 = (lane + 64 < cnt) ? s_p[wid][lane + 64] * 0.0625f : NEG;
    float mx = fmaxf(x0, x1);
#pragma unroll
    for (int off = 32; off; off >>= 1) mx = fmaxf(mx, __shfl_xor(mx, off));
    float p0 = (lane < cnt) ? expf(x0 - mx) : 0.f;
    float p1 = (lane + 64 < cnt) ? expf(x1 - mx) : 0.f;
    float d0 = (lane < cnt) ? s_du[wid][lane] : 0.f;
    float d1 = (lane + 64 < cnt) ? s_du[wid][lane + 64] : 0.f;
    float ps = p0 + p1, ds = p0 * d0 + p1 * d1;
#pragma unroll
    for (int off = 32; off; off >>= 1) { ps += __shfl_xor(ps, off); ds += __shfl_xor(ds, off); }
    float inv = 1.f / ps;
    if (lane < cnt) s_p[wid][lane] = p0 * inv;
    if (lane + 64 < cnt) s_p[wid][lane + 64] = p1 * inv;

    // PV: lane owns 4 output channels
    const unsigned short* Vb = V + (((size_t)b) << 12) * CC;
    float a0 = 0.f, a1 = 0.f, a2 = 0.f, a3 = 0.f;
    for (int i = 0; i < cnt; ++i) {
        float w = s_p[wid][i];
        ushort4 vv = *(const ushort4*)(Vb + (size_t)s_m[wid][i] * CC + lane * 4);
        a0 += w * bf2f(vv.x); a1 += w * bf2f(vv.y);
        a2 += w * bf2f(vv.z); a3 += w * bf2f(vv.w);
    }
    ushort4 o = make_ushort4(f2bf(a0), f2bf(a1), f2bf(a2), f2bf(a3));
    *(ushort4*)(MT + (size_t)bn * CC + lane * 4) = o;
    if (lane == 0) { out1[bn] = ds * inv; out2[bn] = 1.f; }
}

extern "C" void kernel_launch(void* const* d_in, const int* in_sizes, int n_in,
                              void* d_out, int out_size, void* d_ws, size_t ws_size,
                              hipStream_t stream) {
    const float* nodes_L = (const float*)d_in[0];
    const float* nodes_R = (const float*)d_in[1];
    const float* kpts_L  = (const float*)d_in[2];
    const float* kpts_R  = (const float*)d_in[3];
    const float* Wq = (const float*)d_in[4];
    const float* bq = (const float*)d_in[5];
    const float* Wk = (const float*)d_in[6];
    const float* bk = (const float*)d_in[7];
    const float* Wv = (const float*)d_in[8];
    const float* bv = (const float*)d_in[9];
    const float* Wm = (const float*)d_in[10];
    const float* bm = (const float*)d_in[11];

    char* ws = (char*)d_ws;
    unsigned short* Wbf = (unsigned short*)ws; ws += (size_t)4 * 65536 * 2;
    unsigned short* Qp  = (unsigned short*)ws; ws += (size_t)BB * NN * CC * 2;
    unsigned short* Kp  = (unsigned short*)ws; ws += (size_t)BB * MM * CC * 2;
    unsigned short* Vp  = (unsigned short*)ws; ws += (size_t)BB * MM * CC * 2;
    unsigned short* MT  = (unsigned short*)ws; ws += (size_t)BB * NN * CC * 2;
    float* Vsum = (float*)ws;        ws += (size_t)BB * CC * 4;
    float* Usum = (float*)ws;        ws += (size_t)BB * 4;
    float2* sortedUV = (float2*)ws;  ws += (size_t)BB * MM * 8;
    int* binStart = (int*)ws;        ws += (size_t)BB * (NBIN + 1) * 4;
    unsigned short* sortedM = (unsigned short*)ws; ws += (size_t)BB * MM * 2;
    int* hist = (int*)ws;            ws += (size_t)BB * NCH * NBIN * 4;
    int* chunkOff = (int*)ws;        ws += (size_t)BB * NCH * NBIN * 4;
    unsigned short* prank = (unsigned short*)ws;

    float* out0 = (float*)d_out;
    float* out1 = out0 + (size_t)BB * NN * CC;
    float* out2 = out1 + (size_t)BB * NN;

    hipMemsetAsync(Vsum, 0, (size_t)BB * CC * sizeof(float), stream);

    wprep_kernel<<<dim3(256), dim3(256), 0, stream>>>(Wq, Wk, Wv, Wm, Wbf);

    proj_mfma_kernel<false, true, false><<<dim3(128), dim3(256), 0, stream>>>(
        nodes_L, Wbf, bq, Qp, nullptr);
    proj_mfma_kernel<false, true, false><<<dim3(128), dim3(256), 0, stream>>>(
        nodes_R, Wbf + 65536, bk, Kp, nullptr);
    proj_mfma_kernel<false, true, true><<<dim3(128), dim3(256), 0, stream>>>(
        nodes_R, Wbf + 131072, bv, Vp, Vsum);

    bin_count_kernel<<<dim3(NCH, BB), dim3(256), 0, stream>>>(kpts_R, hist, prank);
    bin_scan_kernel<<<dim3(BB), dim3(NBIN), 0, stream>>>(hist, binStart, chunkOff);
    bin_place_kernel<<<dim3(NCH, BB), dim3(256), 0, stream>>>(
        kpts_R, chunkOff, prank, sortedM, sortedUV);
    urmean_kernel<<<dim3(BB), dim3(256), 0, stream>>>(kpts_R, Usum);

    attn_kernel<<<dim3(BB * NN / 4), dim3(256), 0, stream>>>(
        Qp, Kp, Vp, kpts_L, binStart, sortedM, sortedUV, Vsum, Usum, MT, out1, out2);

    proj_mfma_kernel<true, false, false><<<dim3(128), dim3(256), 0, stream>>>(
        MT, Wbf + 196608, bm, out0, nullptr);
}

// Round 4
// 128.313 us; speedup vs baseline: 3.8293x; 1.2505x over previous
//
#include <hip/hip_runtime.h>
#include <hip/hip_bf16.h>

#define BB 4
#define NN 4096
#define MM 4096
#define CC 256
#define CAP 128
#define NBIN 384
#define NCH 16
#define CHK 256

typedef __attribute__((ext_vector_type(8))) short bf16x8;
typedef __attribute__((ext_vector_type(4))) float f32x4;

static __device__ __forceinline__ float bf2f(unsigned short u) {
    return __uint_as_float(((unsigned)u) << 16);
}
static __device__ __forceinline__ unsigned short f2bf(float f) {
    unsigned u = __float_as_uint(f);
    u += 0x7fffu + ((u >> 16) & 1u);   // round-to-nearest-even
    return (unsigned short)(u >> 16);
}

// ---------------- W fp32 -> bf16, packed in MFMA-fragment order ----------------
// Wpk[w][kk][t][lane][j] = W[w][t*16 + (lane&15)][kk*32 + (lane>>4)*8 + j]
// => per (kk,t) the wave's 64x16B B-fragment is 1 KB contiguous (coalesced broadcast).
__global__ void wprep_kernel(const float* __restrict__ Wq, const float* __restrict__ Wk,
                             const float* __restrict__ Wv, const float* __restrict__ Wm,
                             unsigned short* __restrict__ Wpk) {
    int w = blockIdx.y;
    const float* S = (w == 0) ? Wq : (w == 1) ? Wk : (w == 2) ? Wv : Wm;
    int o = blockIdx.x * 256 + threadIdx.x;      // output element in [0,65536)
    int j = o & 7, lane = (o >> 3) & 63, kt = o >> 9;
    int kk = kt >> 4, t = kt & 15;
    int lrow = lane & 15, lk = lane >> 4;
    int r = t * 16 + lrow, c = kk * 32 + lk * 8 + j;
    Wpk[(size_t)w * 65536 + o] = f2bf(S[r * 256 + c]);
}

// ---------------- MFMA projection: O = A @ W^T + b ----------------
// 64 rows/block, 4 waves x 16 rows, K=256 (8 k-steps), N=256 (16 n-tiles).
// blockIdx.y selects (A, W, bias, Out) so Q/K/V run as one dispatch.
template <bool IN_BF16, bool OUT_BF16>
__global__ __launch_bounds__(256, 3) void proj_mfma_kernel(
    const void* __restrict__ A0, const void* __restrict__ A1, const void* __restrict__ A2,
    const unsigned short* __restrict__ Wpk,
    const float* __restrict__ b0, const float* __restrict__ b1, const float* __restrict__ b2,
    void* __restrict__ O0, void* __restrict__ O1, void* __restrict__ O2,
    float* __restrict__ Vsum)
{
    __shared__ unsigned short As[64 * 256];   // 32 KB, XOR-swizzled (16B granule)
    const int tid = threadIdx.x;
    const int y = blockIdx.y;
    const void* Ain = (y == 0) ? A0 : (y == 1) ? A1 : A2;
    const float* bias = (y == 0) ? b0 : (y == 1) ? b1 : b2;
    void* Out = (y == 0) ? O0 : (y == 1) ? O1 : O2;
    const unsigned short* W = Wpk + (size_t)y * 65536;
    const size_t r0 = (size_t)blockIdx.x * 64;

    if constexpr (!IN_BF16) {
        const float* A = (const float*)Ain + r0 * CC;
#pragma unroll
        for (int it = 0; it < 8; ++it) {
            int idx = it * 2048 + tid * 8;
            float4 f0 = *(const float4*)(A + idx);
            float4 f1 = *(const float4*)(A + idx + 4);
            int row = idx >> 8, col = idx & 255;
            int off = row * 512 + ((col * 2) ^ ((row & 7) << 4));
            ushort4* dst = (ushort4*)((char*)As + off);
            dst[0] = make_ushort4(f2bf(f0.x), f2bf(f0.y), f2bf(f0.z), f2bf(f0.w));
            dst[1] = make_ushort4(f2bf(f1.x), f2bf(f1.y), f2bf(f1.z), f2bf(f1.w));
        }
    } else {
        const unsigned short* A = (const unsigned short*)Ain + r0 * CC;
#pragma unroll
        for (int it = 0; it < 8; ++it) {
            int idx = it * 2048 + tid * 8;
            uint4 d = *(const uint4*)(A + idx);
            int row = idx >> 8, col = idx & 255;
            int off = row * 512 + ((col * 2) ^ ((row & 7) << 4));
            *(uint4*)((char*)As + off) = d;
        }
    }
    __syncthreads();

    const int wid = tid >> 6, lane = tid & 63;
    const int lrow = lane & 15, lk = lane >> 4;
    const int xr = (lrow & 7) << 4;
    const int arow = wid * 16 + lrow;

    f32x4 acc[16];
#pragma unroll
    for (int t = 0; t < 16; ++t) acc[t] = (f32x4){0.f, 0.f, 0.f, 0.f};

    const char* asb = (const char*)As;
#pragma unroll
    for (int kk = 0; kk < 8; ++kk) {
        bf16x8 a = *(const bf16x8*)(asb + arow * 512 + ((kk * 64 + lk * 16) ^ xr));
        const bf16x8* wp = (const bf16x8*)(W + (size_t)kk * 8192) + lane;
#pragma unroll
        for (int t = 0; t < 16; ++t) {
            bf16x8 bfrag = wp[t * 64];
            acc[t] = __builtin_amdgcn_mfma_f32_16x16x32_bf16(a, bfrag, acc[t], 0, 0, 0);
        }
    }

    // V column sums for the all-masked fallback path (QKV launch, y==2 only)
    if (Vsum && y == 2) {
#pragma unroll
        for (int t = 0; t < 16; ++t) {
            float vs = acc[t][0] + acc[t][1] + acc[t][2] + acc[t][3];
            vs += __shfl_xor(vs, 16);
            vs += __shfl_xor(vs, 32);
            if (lk == 0) {
                int col = t * 16 + lrow;
                atomicAdd(&Vsum[(blockIdx.x >> 6) * CC + col], vs + 16.f * bias[col]);
            }
        }
    }

    if constexpr (OUT_BF16) {
        __syncthreads();   // done reading As; reuse as bounce buffer
#pragma unroll
        for (int t = 0; t < 16; ++t) {
            int col = t * 16 + lrow;
            float bb = bias[col];
#pragma unroll
            for (int rr = 0; rr < 4; ++rr) {
                int row = wid * 16 + lk * 4 + rr;
                int off = row * 512 + ((col * 2) ^ ((row & 7) << 4));
                *(unsigned short*)((char*)As + off) = f2bf(acc[t][rr] + bb);
            }
        }
        __syncthreads();
        unsigned short* O = (unsigned short*)Out + r0 * CC;
#pragma unroll
        for (int it = 0; it < 8; ++it) {
            int idx = it * 2048 + tid * 8;
            int row = idx >> 8, col = idx & 255;
            int off = row * 512 + ((col * 2) ^ ((row & 7) << 4));
            *(uint4*)(O + idx) = *(const uint4*)((const char*)As + off);
        }
    } else {
        float* O = (float*)Out + r0 * CC;
#pragma unroll
        for (int t = 0; t < 16; ++t) {
            int col = t * 16 + lrow;
            float bb = bias[col];
#pragma unroll
            for (int rr = 0; rr < 4; ++rr) {
                int row = wid * 16 + lk * 4 + rr;
                O[(size_t)row * CC + col] = acc[t][rr] + bb;
            }
        }
    }
}

// ---------------- deterministic chunked counting sort by v-bin ----------------
__global__ __launch_bounds__(256) void bin_count_kernel(
    const float* __restrict__ kptsR, int* __restrict__ hist,
    unsigned short* __restrict__ prank)
{
    __shared__ int h[NBIN];
    __shared__ short sbin[CHK];
    int tid = threadIdx.x, chunk = blockIdx.x, b = blockIdx.y;
    for (int i = tid; i < NBIN; i += CHK) h[i] = 0;
    int m = chunk * CHK + tid;
    float2 p = ((const float2*)kptsR)[(size_t)b * MM + m];
    int bin = (int)p.y;
    sbin[tid] = (short)bin;
    __syncthreads();
    atomicAdd(&h[bin], 1);
    int r = 0;
    for (int t = 0; t < tid; ++t) r += (sbin[t] == bin);
    prank[(b << 12) + m] = (unsigned short)r;
    __syncthreads();
    for (int i = tid; i < NBIN; i += CHK)
        hist[((size_t)b * NCH + chunk) * NBIN + i] = h[i];
}

__global__ __launch_bounds__(NBIN) void bin_scan_kernel(
    const int* __restrict__ hist, int* __restrict__ binStart, int* __restrict__ chunkOff)
{
    __shared__ int sc[NBIN];
    int b = blockIdx.x, v = threadIdx.x;
    int per[NCH];
    int tot = 0;
#pragma unroll
    for (int c = 0; c < NCH; ++c) { per[c] = hist[((size_t)b * NCH + c) * NBIN + v]; tot += per[c]; }
    sc[v] = tot;
    __syncthreads();
    for (int off = 1; off < NBIN; off <<= 1) {
        int t = (v >= off) ? sc[v - off] : 0;
        __syncthreads();
        sc[v] += t;
        __syncthreads();
    }
    int start = v ? sc[v - 1] : 0;
    binStart[b * (NBIN + 1) + v] = start;
    if (v == NBIN - 1) binStart[b * (NBIN + 1) + NBIN] = sc[NBIN - 1];
    int run = start;
#pragma unroll
    for (int c = 0; c < NCH; ++c) {
        chunkOff[((size_t)b * NCH + c) * NBIN + v] = run;
        run += per[c];
    }
}

__global__ __launch_bounds__(256) void bin_place_kernel(
    const float* __restrict__ kptsR, const int* __restrict__ chunkOff,
    const unsigned short* __restrict__ prank,
    unsigned short* __restrict__ sortedM, float2* __restrict__ sortedUV)
{
    int tid = threadIdx.x, chunk = blockIdx.x, b = blockIdx.y;
    int m = chunk * CHK + tid;
    float2 p = ((const float2*)kptsR)[(size_t)b * MM + m];
    int bin = (int)p.y;
    int pos = chunkOff[((size_t)b * NCH + chunk) * NBIN + bin] + prank[(b << 12) + m];
    sortedM[(b << 12) + pos] = (unsigned short)m;
    sortedUV[(b << 12) + pos] = p;
}

// ---------------- mean of u_R per batch ----------------
__global__ __launch_bounds__(256) void urmean_kernel(const float* __restrict__ kptsR,
                                                     float* __restrict__ Usum) {
    int b = blockIdx.x;
    int tid = threadIdx.x;
    float s = 0.f;
    for (int m = tid; m < MM; m += 256) s += kptsR[((size_t)b * MM + m) * 2 + 0];
#pragma unroll
    for (int off = 32; off; off >>= 1) s += __shfl_xor(s, off);
    __shared__ float sr[4];
    int wave = tid >> 6, lane = tid & 63;
    if (lane == 0) sr[wave] = s;
    __syncthreads();
    if (tid == 0) Usum[b] = sr[0] + sr[1] + sr[2] + sr[3];
}

// ---------------- sparse attention: one wave per query row ----------------
__global__ __launch_bounds__(256) void attn_kernel(
    const unsigned short* __restrict__ Q, const unsigned short* __restrict__ K,
    const unsigned short* __restrict__ V,
    const float* __restrict__ kptsL,
    const int* __restrict__ binStart, const unsigned short* __restrict__ sortedM,
    const float2* __restrict__ sortedUV,
    const float* __restrict__ Vsum, const float* __restrict__ Usum,
    unsigned short* __restrict__ MT, float* __restrict__ out1, float* __restrict__ out2)
{
    __shared__ unsigned short s_m[4][CAP];
    __shared__ float s_du[4][CAP];
    __shared__ float s_p[4][CAP];

    const int wid = threadIdx.x >> 6, lane = threadIdx.x & 63;
    const int bn = blockIdx.x * 4 + wid;
    const int b = bn >> 12;

    float2 kl = *(const float2*)(kptsL + (size_t)bn * 2);
    float uL = kl.x, vL = kl.y;

    int ifl = (int)vL;
    int v0 = max(0, ifl - 3), v1 = min(NBIN - 1, ifl + 3);
    int s = binStart[b * (NBIN + 1) + v0];
    int e = binStart[b * (NBIN + 1) + v1 + 1];

    int cnt = 0;
    for (int i0 = s; i0 < e; i0 += 64) {
        int i = i0 + lane;
        bool valid = false;
        float du = 0.f;
        int m = 0;
        if (i < e) {
            float2 uv = sortedUV[(b << 12) + i];
            m = sortedM[(b << 12) + i];
            du = uL - uv.x;
            float dv = fabsf(vL - uv.y);
            valid = (dv < 3.0f) && (du > 0.0f) && (du < 192.0f);
        }
        unsigned long long bal = __ballot(valid);
        int pos = cnt + __popcll(bal & ((1ull << lane) - 1ull));
        if (valid && pos < CAP) { s_m[wid][pos] = (unsigned short)m; s_du[wid][pos] = du; }
        cnt += __popcll(bal);
    }
    if (cnt > CAP) cnt = CAP;

    if (cnt == 0) {
        float4 vs = *(const float4*)(Vsum + b * CC + lane * 4);
        ushort4 o = make_ushort4(f2bf(vs.x * (1.f / MM)), f2bf(vs.y * (1.f / MM)),
                                 f2bf(vs.z * (1.f / MM)), f2bf(vs.w * (1.f / MM)));
        *(ushort4*)(MT + (size_t)bn * CC + lane * 4) = o;
        if (lane == 0) { out1[bn] = uL - Usum[b] * (1.f / MM); out2[bn] = 0.f; }
        return;
    }

    ushort4 qu = *(const ushort4*)(Q + (size_t)bn * CC + lane * 4);
    float q0 = bf2f(qu.x), q1 = bf2f(qu.y), q2 = bf2f(qu.z), q3 = bf2f(qu.w);
    const unsigned short* Kb = K + (((size_t)b) << 12) * CC;
    for (int i = 0; i < cnt; ++i) {
        ushort4 kv = *(const ushort4*)(Kb + (size_t)s_m[wid][i] * CC + lane * 4);
        float d = q0 * bf2f(kv.x) + q1 * bf2f(kv.y) + q2 * bf2f(kv.z) + q3 * bf2f(kv.w);
#pragma unroll
        for (int off = 32; off; off >>= 1) d += __shfl_xor(d, off);
        if (lane == 0) s_p[wid][i] = d;
    }

    const float NEG = -3.0e38f;
    float x0 = (lane < cnt) ? s_p[wid][lane] * 0.0625f : NEG;
    float x1 = (lane + 64 < cnt) ? s_p[wid][lane + 64] * 0.0625f : NEG;
    float mx = fmaxf(x0, x1);
#pragma unroll
    for (int off = 32; off; off >>= 1) mx = fmaxf(mx, __shfl_xor(mx, off));
    float p0 = (lane < cnt) ? expf(x0 - mx) : 0.f;
    float p1 = (lane + 64 < cnt) ? expf(x1 - mx) : 0.f;
    float d0 = (lane < cnt) ? s_du[wid][lane] : 0.f;
    float d1 = (lane + 64 < cnt) ? s_du[wid][lane + 64] : 0.f;
    float ps = p0 + p1, ds = p0 * d0 + p1 * d1;
#pragma unroll
    for (int off = 32; off; off >>= 1) { ps += __shfl_xor(ps, off); ds += __shfl_xor(ds, off); }
    float inv = 1.f / ps;
    if (lane < cnt) s_p[wid][lane] = p0 * inv;
    if (lane + 64 < cnt) s_p[wid][lane + 64] = p1 * inv;

    const unsigned short* Vb = V + (((size_t)b) << 12) * CC;
    float a0 = 0.f, a1 = 0.f, a2 = 0.f, a3 = 0.f;
    for (int i = 0; i < cnt; ++i) {
        float w = s_p[wid][i];
        ushort4 vv = *(const ushort4*)(Vb + (size_t)s_m[wid][i] * CC + lane * 4);
        a0 += w * bf2f(vv.x); a1 += w * bf2f(vv.y);
        a2 += w * bf2f(vv.z); a3 += w * bf2f(vv.w);
    }
    ushort4 o = make_ushort4(f2bf(a0), f2bf(a1), f2bf(a2), f2bf(a3));
    *(ushort4*)(MT + (size_t)bn * CC + lane * 4) = o;
    if (lane == 0) { out1[bn] = ds * inv; out2[bn] = 1.f; }
}

extern "C" void kernel_launch(void* const* d_in, const int* in_sizes, int n_in,
                              void* d_out, int out_size, void* d_ws, size_t ws_size,
                              hipStream_t stream) {
    const float* nodes_L = (const float*)d_in[0];
    const float* nodes_R = (const float*)d_in[1];
    const float* kpts_L  = (const float*)d_in[2];
    const float* kpts_R  = (const float*)d_in[3];
    const float* Wq = (const float*)d_in[4];
    const float* bq = (const float*)d_in[5];
    const float* Wk = (const float*)d_in[6];
    const float* bk = (const float*)d_in[7];
    const float* Wv = (const float*)d_in[8];
    const float* bv = (const float*)d_in[9];
    const float* Wm = (const float*)d_in[10];
    const float* bm = (const float*)d_in[11];

    char* ws = (char*)d_ws;
    unsigned short* Wpk = (unsigned short*)ws; ws += (size_t)4 * 65536 * 2;
    unsigned short* Qp  = (unsigned short*)ws; ws += (size_t)BB * NN * CC * 2;
    unsigned short* Kp  = (unsigned short*)ws; ws += (size_t)BB * MM * CC * 2;
    unsigned short* Vp  = (unsigned short*)ws; ws += (size_t)BB * MM * CC * 2;
    unsigned short* MT  = (unsigned short*)ws; ws += (size_t)BB * NN * CC * 2;
    float* Vsum = (float*)ws;        ws += (size_t)BB * CC * 4;
    float* Usum = (float*)ws;        ws += (size_t)BB * 4;
    float2* sortedUV = (float2*)ws;  ws += (size_t)BB * MM * 8;
    int* binStart = (int*)ws;        ws += (size_t)BB * (NBIN + 1) * 4;
    unsigned short* sortedM = (unsigned short*)ws; ws += (size_t)BB * MM * 2;
    int* hist = (int*)ws;            ws += (size_t)BB * NCH * NBIN * 4;
    int* chunkOff = (int*)ws;        ws += (size_t)BB * NCH * NBIN * 4;
    unsigned short* prank = (unsigned short*)ws;

    float* out0 = (float*)d_out;
    float* out1 = out0 + (size_t)BB * NN * CC;
    float* out2 = out1 + (size_t)BB * NN;

    hipMemsetAsync(Vsum, 0, (size_t)BB * CC * sizeof(float), stream);

    wprep_kernel<<<dim3(256, 4), dim3(256), 0, stream>>>(Wq, Wk, Wv, Wm, Wpk);

    // fused Q/K/V projections (blockIdx.y = 0/1/2)
    proj_mfma_kernel<false, true><<<dim3(256, 3), dim3(256), 0, stream>>>(
        nodes_L, nodes_R, nodes_R, Wpk, bq, bk, bv, Qp, Kp, Vp, Vsum);

    bin_count_kernel<<<dim3(NCH, BB), dim3(256), 0, stream>>>(kpts_R, hist, prank);
    bin_scan_kernel<<<dim3(BB), dim3(NBIN), 0, stream>>>(hist, binStart, chunkOff);
    bin_place_kernel<<<dim3(NCH, BB), dim3(256), 0, stream>>>(
        kpts_R, chunkOff, prank, sortedM, sortedUV);
    urmean_kernel<<<dim3(BB), dim3(256), 0, stream>>>(kpts_R, Usum);

    attn_kernel<<<dim3(BB * NN / 4), dim3(256), 0, stream>>>(
        Qp, Kp, Vp, kpts_L, binStart, sortedM, sortedUV, Vsum, Usum, MT, out1, out2);

    // final projection: out0 = MT @ Wm^T + bm (fp32 out)
    proj_mfma_kernel<true, false><<<dim3(256, 1), dim3(256), 0, stream>>>(
        MT, nullptr, nullptr, Wpk + 3 * 65536, bm, nullptr, nullptr,
        out0, nullptr, nullptr, nullptr);
}

// Round 5
// 116.822 us; speedup vs baseline: 4.2059x; 1.0984x over previous
//
#include <hip/hip_runtime.h>
#include <hip/hip_bf16.h>

#define BB 4
#define NN 4096
#define MM 4096
#define CC 256
#define CAP 128
#define NBIN 384
#define NCH 16
#define CHK 256

typedef __attribute__((ext_vector_type(8))) short bf16x8;
typedef __attribute__((ext_vector_type(4))) float f32x4;

static __device__ __forceinline__ float bf2f(unsigned short u) {
    return __uint_as_float(((unsigned)u) << 16);
}
static __device__ __forceinline__ unsigned short f2bf(float f) {
    unsigned u = __float_as_uint(f);
    u += 0x7fffu + ((u >> 16) & 1u);   // round-to-nearest-even
    return (unsigned short)(u >> 16);
}

// async global->LDS, 16B per lane; LDS dest is wave-uniform base + lane*16
static __device__ __forceinline__ void gload16(const unsigned short* g, unsigned short* l) {
    __builtin_amdgcn_global_load_lds(
        (const __attribute__((address_space(1))) unsigned int*)g,
        (__attribute__((address_space(3))) unsigned int*)l, 16, 0, 0);
}

// ---------------- W fp32 -> bf16, packed in MFMA-fragment order ----------------
// Wpk[w][kk][t][lane][j] = W[w][t*16 + (lane&15)][kk*32 + (lane>>4)*8 + j]
__global__ void wprep_kernel(const float* __restrict__ Wq, const float* __restrict__ Wk,
                             const float* __restrict__ Wv, const float* __restrict__ Wm,
                             unsigned short* __restrict__ Wpk) {
    int w = blockIdx.y;
    const float* S = (w == 0) ? Wq : (w == 1) ? Wk : (w == 2) ? Wv : Wm;
    int o = blockIdx.x * 256 + threadIdx.x;      // output element in [0,65536)
    int j = o & 7, lane = (o >> 3) & 63, kt = o >> 9;
    int kk = kt >> 4, t = kt & 15;
    int lrow = lane & 15, lk = lane >> 4;
    int r = t * 16 + lrow, c = kk * 32 + lk * 8 + j;
    Wpk[(size_t)w * 65536 + o] = f2bf(S[r * 256 + c]);
}

// ---------------- MFMA projection: O = A @ W^T + b ----------------
// 64 rows/block, 4 waves x 16 rows, K=256 (8 k-steps), N=256 (16 n-tiles).
// W k-slices (16 KB) staged to LDS once per block, double-buffered via
// global_load_lds with prefetch distance 1. blockIdx.y selects A/W/bias/Out.
template <bool IN_BF16, bool OUT_BF16>
__global__ __launch_bounds__(256, 2) void proj_mfma_kernel(
    const void* __restrict__ A0, const void* __restrict__ A1, const void* __restrict__ A2,
    const unsigned short* __restrict__ Wpk,
    const float* __restrict__ b0, const float* __restrict__ b1, const float* __restrict__ b2,
    void* __restrict__ O0, void* __restrict__ O1, void* __restrict__ O2,
    float* __restrict__ Vsum)
{
    __shared__ unsigned short As[64 * 256];     // 32 KB, XOR-swizzled (16B granule)
    __shared__ unsigned short Ws[2][8192];      // 2 x 16 KB W k-slices, linear
    const int tid = threadIdx.x;
    const int y = blockIdx.y;
    const void* Ain = (y == 0) ? A0 : (y == 1) ? A1 : A2;
    const float* bias = (y == 0) ? b0 : (y == 1) ? b1 : b2;
    void* Out = (y == 0) ? O0 : (y == 1) ? O1 : O2;
    const unsigned short* W = Wpk + (size_t)y * 65536;
    const size_t r0 = (size_t)blockIdx.x * 64;

    const int wid = tid >> 6, lane = tid & 63;

    // issue W slice kk=0 prefetch first (latency overlaps A staging below)
#pragma unroll
    for (int i = 0; i < 4; ++i) {
        int seg = wid * 4 + i;                  // 1 KB segment per wave-call
        gload16(W + seg * 512 + lane * 8, &Ws[0][seg * 512]);
    }

    if constexpr (!IN_BF16) {
        const float* A = (const float*)Ain + r0 * CC;
#pragma unroll
        for (int it = 0; it < 8; ++it) {
            int idx = it * 2048 + tid * 8;
            float4 f0 = *(const float4*)(A + idx);
            float4 f1 = *(const float4*)(A + idx + 4);
            int row = idx >> 8, col = idx & 255;
            int off = row * 512 + ((col * 2) ^ ((row & 7) << 4));
            ushort4* dst = (ushort4*)((char*)As + off);
            dst[0] = make_ushort4(f2bf(f0.x), f2bf(f0.y), f2bf(f0.z), f2bf(f0.w));
            dst[1] = make_ushort4(f2bf(f1.x), f2bf(f1.y), f2bf(f1.z), f2bf(f1.w));
        }
    } else {
        const unsigned short* A = (const unsigned short*)Ain + r0 * CC;
#pragma unroll
        for (int it = 0; it < 8; ++it) {
            int idx = it * 2048 + tid * 8;
            uint4 d = *(const uint4*)(A + idx);
            int row = idx >> 8, col = idx & 255;
            int off = row * 512 + ((col * 2) ^ ((row & 7) << 4));
            *(uint4*)((char*)As + off) = d;
        }
    }

    const int lrow = lane & 15, lk = lane >> 4;
    const int xr = (lrow & 7) << 4;
    const int arow = wid * 16 + lrow;

    f32x4 acc[16];
#pragma unroll
    for (int t = 0; t < 16; ++t) acc[t] = (f32x4){0.f, 0.f, 0.f, 0.f};

    const char* asb = (const char*)As;
#pragma unroll
    for (int kk = 0; kk < 8; ++kk) {
        const int cur = kk & 1;
        asm volatile("s_waitcnt vmcnt(0)" ::: "memory");
        __syncthreads();   // Ws[cur] loaded for all; everyone done reading Ws[cur^1]
        if (kk < 7) {
#pragma unroll
            for (int i = 0; i < 4; ++i) {
                int seg = wid * 4 + i;
                gload16(W + (kk + 1) * 8192 + seg * 512 + lane * 8, &Ws[cur ^ 1][seg * 512]);
            }
        }
        bf16x8 a = *(const bf16x8*)(asb + arow * 512 + ((kk * 64 + lk * 16) ^ xr));
        const unsigned short* Wb = Ws[cur];
#pragma unroll
        for (int t = 0; t < 16; ++t) {
            bf16x8 bfrag = *(const bf16x8*)(Wb + t * 512 + lane * 8);
            acc[t] = __builtin_amdgcn_mfma_f32_16x16x32_bf16(a, bfrag, acc[t], 0, 0, 0);
        }
    }

    // V column sums for the all-masked fallback path (QKV launch, y==2 only)
    if (Vsum && y == 2) {
#pragma unroll
        for (int t = 0; t < 16; ++t) {
            float vs = acc[t][0] + acc[t][1] + acc[t][2] + acc[t][3];
            vs += __shfl_xor(vs, 16);
            vs += __shfl_xor(vs, 32);
            if (lk == 0) {
                int col = t * 16 + lrow;
                atomicAdd(&Vsum[(blockIdx.x >> 6) * CC + col], vs + 16.f * bias[col]);
            }
        }
    }

    if constexpr (OUT_BF16) {
        __syncthreads();   // done reading As; reuse as bounce buffer
#pragma unroll
        for (int t = 0; t < 16; ++t) {
            int col = t * 16 + lrow;
            float bb = bias[col];
#pragma unroll
            for (int rr = 0; rr < 4; ++rr) {
                int row = wid * 16 + lk * 4 + rr;
                int off = row * 512 + ((col * 2) ^ ((row & 7) << 4));
                *(unsigned short*)((char*)As + off) = f2bf(acc[t][rr] + bb);
            }
        }
        __syncthreads();
        unsigned short* O = (unsigned short*)Out + r0 * CC;
#pragma unroll
        for (int it = 0; it < 8; ++it) {
            int idx = it * 2048 + tid * 8;
            int row = idx >> 8, col = idx & 255;
            int off = row * 512 + ((col * 2) ^ ((row & 7) << 4));
            *(uint4*)(O + idx) = *(const uint4*)((const char*)As + off);
        }
    } else {
        float* O = (float*)Out + r0 * CC;
#pragma unroll
        for (int t = 0; t < 16; ++t) {
            int col = t * 16 + lrow;
            float bb = bias[col];
#pragma unroll
            for (int rr = 0; rr < 4; ++rr) {
                int row = wid * 16 + lk * 4 + rr;
                O[(size_t)row * CC + col] = acc[t][rr] + bb;
            }
        }
    }
}

// ---------------- deterministic chunked counting sort by v-bin ----------------
__global__ __launch_bounds__(256) void bin_count_kernel(
    const float* __restrict__ kptsR, int* __restrict__ hist,
    unsigned short* __restrict__ prank)
{
    __shared__ int h[NBIN];
    __shared__ short sbin[CHK];
    int tid = threadIdx.x, chunk = blockIdx.x, b = blockIdx.y;
    for (int i = tid; i < NBIN; i += CHK) h[i] = 0;
    int m = chunk * CHK + tid;
    float2 p = ((const float2*)kptsR)[(size_t)b * MM + m];
    int bin = (int)p.y;
    sbin[tid] = (short)bin;
    __syncthreads();
    atomicAdd(&h[bin], 1);
    int r = 0;
    for (int t = 0; t < tid; ++t) r += (sbin[t] == bin);
    prank[(b << 12) + m] = (unsigned short)r;
    __syncthreads();
    for (int i = tid; i < NBIN; i += CHK)
        hist[((size_t)b * NCH + chunk) * NBIN + i] = h[i];
}

__global__ __launch_bounds__(NBIN) void bin_scan_kernel(
    const int* __restrict__ hist, int* __restrict__ binStart, int* __restrict__ chunkOff)
{
    __shared__ int sc[NBIN];
    int b = blockIdx.x, v = threadIdx.x;
    int per[NCH];
    int tot = 0;
#pragma unroll
    for (int c = 0; c < NCH; ++c) { per[c] = hist[((size_t)b * NCH + c) * NBIN + v]; tot += per[c]; }
    sc[v] = tot;
    __syncthreads();
    for (int off = 1; off < NBIN; off <<= 1) {
        int t = (v >= off) ? sc[v - off] : 0;
        __syncthreads();
        sc[v] += t;
        __syncthreads();
    }
    int start = v ? sc[v - 1] : 0;
    binStart[b * (NBIN + 1) + v] = start;
    if (v == NBIN - 1) binStart[b * (NBIN + 1) + NBIN] = sc[NBIN - 1];
    int run = start;
#pragma unroll
    for (int c = 0; c < NCH; ++c) {
        chunkOff[((size_t)b * NCH + c) * NBIN + v] = run;
        run += per[c];
    }
}

__global__ __launch_bounds__(256) void bin_place_kernel(
    const float* __restrict__ kptsR, const int* __restrict__ chunkOff,
    const unsigned short* __restrict__ prank,
    unsigned short* __restrict__ sortedM, float2* __restrict__ sortedUV)
{
    int tid = threadIdx.x, chunk = blockIdx.x, b = blockIdx.y;
    int m = chunk * CHK + tid;
    float2 p = ((const float2*)kptsR)[(size_t)b * MM + m];
    int bin = (int)p.y;
    int pos = chunkOff[((size_t)b * NCH + chunk) * NBIN + bin] + prank[(b << 12) + m];
    sortedM[(b << 12) + pos] = (unsigned short)m;
    sortedUV[(b << 12) + pos] = p;
}

// ---------------- mean of u_R per batch ----------------
__global__ __launch_bounds__(256) void urmean_kernel(const float* __restrict__ kptsR,
                                                     float* __restrict__ Usum) {
    int b = blockIdx.x;
    int tid = threadIdx.x;
    float s = 0.f;
    for (int m = tid; m < MM; m += 256) s += kptsR[((size_t)b * MM + m) * 2 + 0];
#pragma unroll
    for (int off = 32; off; off >>= 1) s += __shfl_xor(s, off);
    __shared__ float sr[4];
    int wave = tid >> 6, lane = tid & 63;
    if (lane == 0) sr[wave] = s;
    __syncthreads();
    if (tid == 0) Usum[b] = sr[0] + sr[1] + sr[2] + sr[3];
}

// ---------------- sparse attention: one wave per query row ----------------
__global__ __launch_bounds__(256) void attn_kernel(
    const unsigned short* __restrict__ Q, const unsigned short* __restrict__ K,
    const unsigned short* __restrict__ V,
    const float* __restrict__ kptsL,
    const int* __restrict__ binStart, const unsigned short* __restrict__ sortedM,
    const float2* __restrict__ sortedUV,
    const float* __restrict__ Vsum, const float* __restrict__ Usum,
    unsigned short* __restrict__ MT, float* __restrict__ out1, float* __restrict__ out2)
{
    __shared__ unsigned short s_m[4][CAP];
    __shared__ float s_du[4][CAP];
    __shared__ float s_p[4][CAP];

    const int wid = threadIdx.x >> 6, lane = threadIdx.x & 63;
    const int bn = blockIdx.x * 4 + wid;
    const int b = bn >> 12;

    float2 kl = *(const float2*)(kptsL + (size_t)bn * 2);
    float uL = kl.x, vL = kl.y;

    int ifl = (int)vL;
    int v0 = max(0, ifl - 3), v1 = min(NBIN - 1, ifl + 3);
    int s = binStart[b * (NBIN + 1) + v0];
    int e = binStart[b * (NBIN + 1) + v1 + 1];

    int cnt = 0;
    for (int i0 = s; i0 < e; i0 += 64) {
        int i = i0 + lane;
        bool valid = false;
        float du = 0.f;
        int m = 0;
        if (i < e) {
            float2 uv = sortedUV[(b << 12) + i];
            m = sortedM[(b << 12) + i];
            du = uL - uv.x;
            float dv = fabsf(vL - uv.y);
            valid = (dv < 3.0f) && (du > 0.0f) && (du < 192.0f);
        }
        unsigned long long bal = __ballot(valid);
        int pos = cnt + __popcll(bal & ((1ull << lane) - 1ull));
        if (valid && pos < CAP) { s_m[wid][pos] = (unsigned short)m; s_du[wid][pos] = du; }
        cnt += __popcll(bal);
    }
    if (cnt > CAP) cnt = CAP;

    if (cnt == 0) {
        float4 vs = *(const float4*)(Vsum + b * CC + lane * 4);
        ushort4 o = make_ushort4(f2bf(vs.x * (1.f / MM)), f2bf(vs.y * (1.f / MM)),
                                 f2bf(vs.z * (1.f / MM)), f2bf(vs.w * (1.f / MM)));
        *(ushort4*)(MT + (size_t)bn * CC + lane * 4) = o;
        if (lane == 0) { out1[bn] = uL - Usum[b] * (1.f / MM); out2[bn] = 0.f; }
        return;
    }

    ushort4 qu = *(const ushort4*)(Q + (size_t)bn * CC + lane * 4);
    float q0 = bf2f(qu.x), q1 = bf2f(qu.y), q2 = bf2f(qu.z), q3 = bf2f(qu.w);
    const unsigned short* Kb = K + (((size_t)b) << 12) * CC;
    for (int i = 0; i < cnt; ++i) {
        ushort4 kv = *(const ushort4*)(Kb + (size_t)s_m[wid][i] * CC + lane * 4);
        float d = q0 * bf2f(kv.x) + q1 * bf2f(kv.y) + q2 * bf2f(kv.z) + q3 * bf2f(kv.w);
#pragma unroll
        for (int off = 32; off; off >>= 1) d += __shfl_xor(d, off);
        if (lane == 0) s_p[wid][i] = d;
    }

    const float NEG = -3.0e38f;
    float x0 = (lane < cnt) ? s_p[wid][lane] * 0.0625f : NEG;
    float x1 = (lane + 64 < cnt) ? s_p[wid][lane + 64] * 0.0625f : NEG;
    float mx = fmaxf(x0, x1);
#pragma unroll
    for (int off = 32; off; off >>= 1) mx = fmaxf(mx, __shfl_xor(mx, off));
    float p0 = (lane < cnt) ? expf(x0 - mx) : 0.f;
    float p1 = (lane + 64 < cnt) ? expf(x1 - mx) : 0.f;
    float d0 = (lane < cnt) ? s_du[wid][lane] : 0.f;
    float d1 = (lane + 64 < cnt) ? s_du[wid][lane + 64] : 0.f;
    float ps = p0 + p1, ds = p0 * d0 + p1 * d1;
#pragma unroll
    for (int off = 32; off; off >>= 1) { ps += __shfl_xor(ps, off); ds += __shfl_xor(ds, off); }
    float inv = 1.f / ps;
    if (lane < cnt) s_p[wid][lane] = p0 * inv;
    if (lane + 64 < cnt) s_p[wid][lane + 64] = p1 * inv;

    const unsigned short* Vb = V + (((size_t)b) << 12) * CC;
    float a0 = 0.f, a1 = 0.f, a2 = 0.f, a3 = 0.f;
    for (int i = 0; i < cnt; ++i) {
        float w = s_p[wid][i];
        ushort4 vv = *(const ushort4*)(Vb + (size_t)s_m[wid][i] * CC + lane * 4);
        a0 += w * bf2f(vv.x); a1 += w * bf2f(vv.y);
        a2 += w * bf2f(vv.z); a3 += w * bf2f(vv.w);
    }
    ushort4 o = make_ushort4(f2bf(a0), f2bf(a1), f2bf(a2), f2bf(a3));
    *(ushort4*)(MT + (size_t)bn * CC + lane * 4) = o;
    if (lane == 0) { out1[bn] = ds * inv; out2[bn] = 1.f; }
}

extern "C" void kernel_launch(void* const* d_in, const int* in_sizes, int n_in,
                              void* d_out, int out_size, void* d_ws, size_t ws_size,
                              hipStream_t stream) {
    const float* nodes_L = (const float*)d_in[0];
    const float* nodes_R = (const float*)d_in[1];
    const float* kpts_L  = (const float*)d_in[2];
    const float* kpts_R  = (const float*)d_in[3];
    const float* Wq = (const float*)d_in[4];
    const float* bq = (const float*)d_in[5];
    const float* Wk = (const float*)d_in[6];
    const float* bk = (const float*)d_in[7];
    const float* Wv = (const float*)d_in[8];
    const float* bv = (const float*)d_in[9];
    const float* Wm = (const float*)d_in[10];
    const float* bm = (const float*)d_in[11];

    char* ws = (char*)d_ws;
    unsigned short* Wpk = (unsigned short*)ws; ws += (size_t)4 * 65536 * 2;
    unsigned short* Qp  = (unsigned short*)ws; ws += (size_t)BB * NN * CC * 2;
    unsigned short* Kp  = (unsigned short*)ws; ws += (size_t)BB * MM * CC * 2;
    unsigned short* Vp  = (unsigned short*)ws; ws += (size_t)BB * MM * CC * 2;
    unsigned short* MT  = (unsigned short*)ws; ws += (size_t)BB * NN * CC * 2;
    float* Vsum = (float*)ws;        ws += (size_t)BB * CC * 4;
    float* Usum = (float*)ws;        ws += (size_t)BB * 4;
    float2* sortedUV = (float2*)ws;  ws += (size_t)BB * MM * 8;
    int* binStart = (int*)ws;        ws += (size_t)BB * (NBIN + 1) * 4;
    unsigned short* sortedM = (unsigned short*)ws; ws += (size_t)BB * MM * 2;
    int* hist = (int*)ws;            ws += (size_t)BB * NCH * NBIN * 4;
    int* chunkOff = (int*)ws;        ws += (size_t)BB * NCH * NBIN * 4;
    unsigned short* prank = (unsigned short*)ws;

    float* out0 = (float*)d_out;
    float* out1 = out0 + (size_t)BB * NN * CC;
    float* out2 = out1 + (size_t)BB * NN;

    hipMemsetAsync(Vsum, 0, (size_t)BB * CC * sizeof(float), stream);

    wprep_kernel<<<dim3(256, 4), dim3(256), 0, stream>>>(Wq, Wk, Wv, Wm, Wpk);

    // fused Q/K/V projections (blockIdx.y = 0/1/2)
    proj_mfma_kernel<false, true><<<dim3(256, 3), dim3(256), 0, stream>>>(
        nodes_L, nodes_R, nodes_R, Wpk, bq, bk, bv, Qp, Kp, Vp, Vsum);

    bin_count_kernel<<<dim3(NCH, BB), dim3(256), 0, stream>>>(kpts_R, hist, prank);
    bin_scan_kernel<<<dim3(BB), dim3(NBIN), 0, stream>>>(hist, binStart, chunkOff);
    bin_place_kernel<<<dim3(NCH, BB), dim3(256), 0, stream>>>(
        kpts_R, chunkOff, prank, sortedM, sortedUV);
    urmean_kernel<<<dim3(BB), dim3(256), 0, stream>>>(kpts_R, Usum);

    attn_kernel<<<dim3(BB * NN / 4), dim3(256), 0, stream>>>(
        Qp, Kp, Vp, kpts_L, binStart, sortedM, sortedUV, Vsum, Usum, MT, out1, out2);

    // final projection: out0 = MT @ Wm^T + bm (fp32 out)
    proj_mfma_kernel<true, false><<<dim3(256, 1), dim3(256), 0, stream>>>(
        MT, nullptr, nullptr, Wpk + 3 * 65536, bm, nullptr, nullptr,
        out0, nullptr, nullptr, nullptr);
}

// Round 6
// 106.379 us; speedup vs baseline: 4.6188x; 1.0982x over previous
//
#include <hip/hip_runtime.h>
#include <hip/hip_bf16.h>

#define BB 4
#define NN 4096
#define MM 4096
#define CC 256
#define CAP 128
#define NBIN 384
#define NCH 16
#define CHK 256

typedef __attribute__((ext_vector_type(8))) short bf16x8;
typedef __attribute__((ext_vector_type(4))) float f32x4;

static __device__ __forceinline__ float bf2f(unsigned short u) {
    return __uint_as_float(((unsigned)u) << 16);
}
static __device__ __forceinline__ unsigned short f2bf(float f) {
    unsigned u = __float_as_uint(f);
    u += 0x7fffu + ((u >> 16) & 1u);   // round-to-nearest-even
    return (unsigned short)(u >> 16);
}
static __device__ __forceinline__ bf16x8 cvt8(float4 x, float4 y) {
    bf16x8 r;
    r[0] = (short)f2bf(x.x); r[1] = (short)f2bf(x.y);
    r[2] = (short)f2bf(x.z); r[3] = (short)f2bf(x.w);
    r[4] = (short)f2bf(y.x); r[5] = (short)f2bf(y.y);
    r[6] = (short)f2bf(y.z); r[7] = (short)f2bf(y.w);
    return r;
}
static __device__ __forceinline__ bf16x8 asbf(uint4 u) {
    union { uint4 a; bf16x8 b; } c; c.a = u; return c.b;
}

// ---------------- W fp32 -> bf16, packed in MFMA-fragment order ----------------
// Wpk[w][kk][t][lane][j] = W[w][t*16 + (lane&15)][kk*32 + (lane>>4)*8 + j]
__global__ void wprep_kernel(const float* __restrict__ Wq, const float* __restrict__ Wk,
                             const float* __restrict__ Wv, const float* __restrict__ Wm,
                             unsigned short* __restrict__ Wpk) {
    int w = blockIdx.y;
    const float* S = (w == 0) ? Wq : (w == 1) ? Wk : (w == 2) ? Wv : Wm;
    int o = blockIdx.x * 256 + threadIdx.x;      // output element in [0,65536)
    int j = o & 7, lane = (o >> 3) & 63, kt = o >> 9;
    int kk = kt >> 4, t = kt & 15;
    int lrow = lane & 15, lk = lane >> 4;
    int r = t * 16 + lrow, c = kk * 32 + lk * 8 + j;
    Wpk[(size_t)w * 65536 + o] = f2bf(S[r * 256 + c]);
}

// ---------------- MFMA projection: O = A @ W^T + b ----------------
// Drain-free streaming pipeline:
//  - wave = 32 rows x 64 cols (4 n-tiles), block = 4 waves = 128 rows, same colgroup
//  - A: global->reg, depth-2 prefetch, fp32->bf16 (or bf16 reinterpret) in regs
//  - W: 4KB k-slice per colgroup, reg->ds_write staged (quarter per wave),
//       double-buffered, ONE raw s_barrier + lgkmcnt(0) per k-step (no vmcnt drains)
//  - bf16 output bounced through LDS for coalesced uint4 stores
template <bool IN_BF16, bool OUT_BF16>
__global__ __launch_bounds__(256, 3) void proj_mfma_kernel(
    const void* __restrict__ A0, const void* __restrict__ A1, const void* __restrict__ A2,
    const unsigned short* __restrict__ Wpk,
    const float* __restrict__ b0, const float* __restrict__ b1, const float* __restrict__ b2,
    void* __restrict__ O0, void* __restrict__ O1, void* __restrict__ O2,
    float* __restrict__ Vsum)
{
    __shared__ __align__(16) unsigned short Ws[2][2048];                 // 2 x 4KB W slice
    __shared__ __align__(16) unsigned short Bo[OUT_BF16 ? 128 * 64 : 8]; // 16KB bounce

    const int tid = threadIdx.x, wid = tid >> 6, lane = tid & 63;
    const int lrow = lane & 15, lk = lane >> 4;
    const int y = blockIdx.y;
    const void* Ain = (y == 0) ? A0 : (y == 1) ? A1 : A2;
    const float* bias = (y == 0) ? b0 : (y == 1) ? b1 : b2;
    void* Out = (y == 0) ? O0 : (y == 1) ? O1 : O2;
    const unsigned short* W = Wpk + (size_t)y * 65536;

    const int g = blockIdx.x & 3;                      // colgroup (64 cols)
    const size_t rblk = (size_t)(blockIdx.x >> 2) * 128;
    const size_t r0 = rblk + (size_t)wid * 32;

    const size_t ar0 = (r0 + lrow) * CC;               // subtile 0 row
    const size_t ar1 = (r0 + 16 + lrow) * CC;          // subtile 1 row
    const int ac = lk * 8;

    const float* Af = (const float*)Ain;
    const unsigned short* Ab = (const unsigned short*)Ain;

    float4 fa[2][4];
    uint4  ba[2][2];
    uint4  wreg[2];

#define LOADA(kk, s)                                                        \
    do {                                                                    \
        if constexpr (!IN_BF16) {                                           \
            const float* p0 = Af + ar0 + (kk) * 32 + ac;                    \
            const float* p1 = Af + ar1 + (kk) * 32 + ac;                    \
            fa[s][0] = *(const float4*)p0; fa[s][1] = *(const float4*)(p0 + 4); \
            fa[s][2] = *(const float4*)p1; fa[s][3] = *(const float4*)(p1 + 4); \
        } else {                                                            \
            ba[s][0] = *(const uint4*)(Ab + ar0 + (kk) * 32 + ac);          \
            ba[s][1] = *(const uint4*)(Ab + ar1 + (kk) * 32 + ac);          \
        }                                                                   \
    } while (0)

#define LOADW(kk, s)                                                        \
    wreg[s] = *(const uint4*)(W + (size_t)(kk) * 8192 + g * 2048 + wid * 512 + lane * 8)

    f32x4 acc[4][2];
#pragma unroll
    for (int t = 0; t < 4; ++t) {
        acc[t][0] = (f32x4){0.f, 0.f, 0.f, 0.f};
        acc[t][1] = (f32x4){0.f, 0.f, 0.f, 0.f};
    }

    LOADW(0, 0);
    LOADA(0, 0);
    LOADA(1, 1);

#pragma unroll
    for (int kk = 0; kk < 8; ++kk) {
        const int cur = kk & 1;
        bf16x8 af0, af1;
        if constexpr (!IN_BF16) {
            af0 = cvt8(fa[cur][0], fa[cur][1]);        // compiler: counted vmcnt wait
            af1 = cvt8(fa[cur][2], fa[cur][3]);
        } else {
            af0 = asbf(ba[cur][0]);
            af1 = asbf(ba[cur][1]);
        }
        // stage this wave's quarter of W slice kk into buf cur
        *(uint4*)&Ws[cur][wid * 512 + lane * 8] = wreg[cur];
        asm volatile("s_waitcnt lgkmcnt(0)" ::: "memory");
        __builtin_amdgcn_sched_barrier(0);
        __builtin_amdgcn_s_barrier();                  // raw barrier: no vmcnt drain
        __builtin_amdgcn_sched_barrier(0);
        if (kk < 7) LOADW(kk + 1, cur ^ 1);
        if (kk < 6) LOADA(kk + 2, cur);
#pragma unroll
        for (int t = 0; t < 4; ++t) {
            bf16x8 wf = *(const bf16x8*)&Ws[cur][t * 512 + lane * 8];
            acc[t][0] = __builtin_amdgcn_mfma_f32_16x16x32_bf16(af0, wf, acc[t][0], 0, 0, 0);
            acc[t][1] = __builtin_amdgcn_mfma_f32_16x16x32_bf16(af1, wf, acc[t][1], 0, 0, 0);
        }
    }
#undef LOADA
#undef LOADW

    // V column sums for the all-masked fallback path (QKV launch, y==2 only)
    if (!IN_BF16 && Vsum != nullptr && y == 2) {
#pragma unroll
        for (int t = 0; t < 4; ++t) {
            int col = g * 64 + t * 16 + lrow;
            float vs = acc[t][0][0] + acc[t][0][1] + acc[t][0][2] + acc[t][0][3]
                     + acc[t][1][0] + acc[t][1][1] + acc[t][1][2] + acc[t][1][3];
            vs += __shfl_xor(vs, 16);
            vs += __shfl_xor(vs, 32);
            if (lk == 0)
                atomicAdd(&Vsum[(r0 >> 12) * CC + col], vs + 32.f * bias[col]);
        }
    }

    if constexpr (OUT_BF16) {
#pragma unroll
        for (int t = 0; t < 4; ++t) {
            float bb = bias[g * 64 + t * 16 + lrow];
#pragma unroll
            for (int s = 0; s < 2; ++s)
#pragma unroll
                for (int rr = 0; rr < 4; ++rr) {
                    int row = wid * 32 + s * 16 + lk * 4 + rr;
                    Bo[row * 64 + t * 16 + lrow] = f2bf(acc[t][s][rr] + bb);
                }
        }
        __syncthreads();
        unsigned short* O = (unsigned short*)Out;
#pragma unroll
        for (int i = 0; i < 4; ++i) {
            int idx = i * 2048 + tid * 8;
            int row = idx >> 6, col = idx & 63;
            *(uint4*)(O + (rblk + row) * CC + g * 64 + col) = *(const uint4*)&Bo[idx];
        }
    } else {
        float* O = (float*)Out;
#pragma unroll
        for (int t = 0; t < 4; ++t) {
            float bb = bias[g * 64 + t * 16 + lrow];
#pragma unroll
            for (int s = 0; s < 2; ++s)
#pragma unroll
                for (int rr = 0; rr < 4; ++rr) {
                    size_t row = r0 + s * 16 + lk * 4 + rr;
                    O[row * CC + g * 64 + t * 16 + lrow] = acc[t][s][rr] + bb;
                }
        }
    }
}

// ---------------- deterministic chunked counting sort by v-bin ----------------
__global__ __launch_bounds__(256) void bin_count_kernel(
    const float* __restrict__ kptsR, int* __restrict__ hist,
    unsigned short* __restrict__ prank)
{
    __shared__ int h[NBIN];
    __shared__ short sbin[CHK];
    int tid = threadIdx.x, chunk = blockIdx.x, b = blockIdx.y;
    for (int i = tid; i < NBIN; i += CHK) h[i] = 0;
    int m = chunk * CHK + tid;
    float2 p = ((const float2*)kptsR)[(size_t)b * MM + m];
    int bin = (int)p.y;
    sbin[tid] = (short)bin;
    __syncthreads();
    atomicAdd(&h[bin], 1);
    int r = 0;
    for (int t = 0; t < tid; ++t) r += (sbin[t] == bin);
    prank[(b << 12) + m] = (unsigned short)r;
    __syncthreads();
    for (int i = tid; i < NBIN; i += CHK)
        hist[((size_t)b * NCH + chunk) * NBIN + i] = h[i];
}

__global__ __launch_bounds__(NBIN) void bin_scan_kernel(
    const int* __restrict__ hist, int* __restrict__ binStart, int* __restrict__ chunkOff)
{
    __shared__ int sc[NBIN];
    int b = blockIdx.x, v = threadIdx.x;
    int per[NCH];
    int tot = 0;
#pragma unroll
    for (int c = 0; c < NCH; ++c) { per[c] = hist[((size_t)b * NCH + c) * NBIN + v]; tot += per[c]; }
    sc[v] = tot;
    __syncthreads();
    for (int off = 1; off < NBIN; off <<= 1) {
        int t = (v >= off) ? sc[v - off] : 0;
        __syncthreads();
        sc[v] += t;
        __syncthreads();
    }
    int start = v ? sc[v - 1] : 0;
    binStart[b * (NBIN + 1) + v] = start;
    if (v == NBIN - 1) binStart[b * (NBIN + 1) + NBIN] = sc[NBIN - 1];
    int run = start;
#pragma unroll
    for (int c = 0; c < NCH; ++c) {
        chunkOff[((size_t)b * NCH + c) * NBIN + v] = run;
        run += per[c];
    }
}

__global__ __launch_bounds__(256) void bin_place_kernel(
    const float* __restrict__ kptsR, const int* __restrict__ chunkOff,
    const unsigned short* __restrict__ prank,
    unsigned short* __restrict__ sortedM, float2* __restrict__ sortedUV)
{
    int tid = threadIdx.x, chunk = blockIdx.x, b = blockIdx.y;
    int m = chunk * CHK + tid;
    float2 p = ((const float2*)kptsR)[(size_t)b * MM + m];
    int bin = (int)p.y;
    int pos = chunkOff[((size_t)b * NCH + chunk) * NBIN + bin] + prank[(b << 12) + m];
    sortedM[(b << 12) + pos] = (unsigned short)m;
    sortedUV[(b << 12) + pos] = p;
}

// ---------------- mean of u_R per batch ----------------
__global__ __launch_bounds__(256) void urmean_kernel(const float* __restrict__ kptsR,
                                                     float* __restrict__ Usum) {
    int b = blockIdx.x;
    int tid = threadIdx.x;
    float s = 0.f;
    for (int m = tid; m < MM; m += 256) s += kptsR[((size_t)b * MM + m) * 2 + 0];
#pragma unroll
    for (int off = 32; off; off >>= 1) s += __shfl_xor(s, off);
    __shared__ float sr[4];
    int wave = tid >> 6, lane = tid & 63;
    if (lane == 0) sr[wave] = s;
    __syncthreads();
    if (tid == 0) Usum[b] = sr[0] + sr[1] + sr[2] + sr[3];
}

// ---------------- sparse attention: one wave per query row ----------------
__global__ __launch_bounds__(256) void attn_kernel(
    const unsigned short* __restrict__ Q, const unsigned short* __restrict__ K,
    const unsigned short* __restrict__ V,
    const float* __restrict__ kptsL,
    const int* __restrict__ binStart, const unsigned short* __restrict__ sortedM,
    const float2* __restrict__ sortedUV,
    const float* __restrict__ Vsum, const float* __restrict__ Usum,
    unsigned short* __restrict__ MT, float* __restrict__ out1, float* __restrict__ out2)
{
    __shared__ unsigned short s_m[4][CAP];
    __shared__ float s_du[4][CAP];
    __shared__ float s_p[4][CAP];

    const int wid = threadIdx.x >> 6, lane = threadIdx.x & 63;
    const int bn = blockIdx.x * 4 + wid;
    const int b = bn >> 12;

    float2 kl = *(const float2*)(kptsL + (size_t)bn * 2);
    float uL = kl.x, vL = kl.y;

    int ifl = (int)vL;
    int v0 = max(0, ifl - 3), v1 = min(NBIN - 1, ifl + 3);
    int s = binStart[b * (NBIN + 1) + v0];
    int e = binStart[b * (NBIN + 1) + v1 + 1];

    int cnt = 0;
    for (int i0 = s; i0 < e; i0 += 64) {
        int i = i0 + lane;
        bool valid = false;
        float du = 0.f;
        int m = 0;
        if (i < e) {
            float2 uv = sortedUV[(b << 12) + i];
            m = sortedM[(b << 12) + i];
            du = uL - uv.x;
            float dv = fabsf(vL - uv.y);
            valid = (dv < 3.0f) && (du > 0.0f) && (du < 192.0f);
        }
        unsigned long long bal = __ballot(valid);
        int pos = cnt + __popcll(bal & ((1ull << lane) - 1ull));
        if (valid && pos < CAP) { s_m[wid][pos] = (unsigned short)m; s_du[wid][pos] = du; }
        cnt += __popcll(bal);
    }
    if (cnt > CAP) cnt = CAP;

    if (cnt == 0) {
        float4 vs = *(const float4*)(Vsum + b * CC + lane * 4);
        ushort4 o = make_ushort4(f2bf(vs.x * (1.f / MM)), f2bf(vs.y * (1.f / MM)),
                                 f2bf(vs.z * (1.f / MM)), f2bf(vs.w * (1.f / MM)));
        *(ushort4*)(MT + (size_t)bn * CC + lane * 4) = o;
        if (lane == 0) { out1[bn] = uL - Usum[b] * (1.f / MM); out2[bn] = 0.f; }
        return;
    }

    ushort4 qu = *(const ushort4*)(Q + (size_t)bn * CC + lane * 4);
    float q0 = bf2f(qu.x), q1 = bf2f(qu.y), q2 = bf2f(qu.z), q3 = bf2f(qu.w);
    const unsigned short* Kb = K + (((size_t)b) << 12) * CC;
    for (int i = 0; i < cnt; ++i) {
        ushort4 kv = *(const ushort4*)(Kb + (size_t)s_m[wid][i] * CC + lane * 4);
        float d = q0 * bf2f(kv.x) + q1 * bf2f(kv.y) + q2 * bf2f(kv.z) + q3 * bf2f(kv.w);
#pragma unroll
        for (int off = 32; off; off >>= 1) d += __shfl_xor(d, off);
        if (lane == 0) s_p[wid][i] = d;
    }

    const float NEG = -3.0e38f;
    float x0 = (lane < cnt) ? s_p[wid][lane] * 0.0625f : NEG;
    float x1 = (lane + 64 < cnt) ? s_p[wid][lane + 64] * 0.0625f : NEG;
    float mx = fmaxf(x0, x1);
#pragma unroll
    for (int off = 32; off; off >>= 1) mx = fmaxf(mx, __shfl_xor(mx, off));
    float p0 = (lane < cnt) ? expf(x0 - mx) : 0.f;
    float p1 = (lane + 64 < cnt) ? expf(x1 - mx) : 0.f;
    float d0 = (lane < cnt) ? s_du[wid][lane] : 0.f;
    float d1 = (lane + 64 < cnt) ? s_du[wid][lane + 64] : 0.f;
    float ps = p0 + p1, ds = p0 * d0 + p1 * d1;
#pragma unroll
    for (int off = 32; off; off >>= 1) { ps += __shfl_xor(ps, off); ds += __shfl_xor(ds, off); }
    float inv = 1.f / ps;
    if (lane < cnt) s_p[wid][lane] = p0 * inv;
    if (lane + 64 < cnt) s_p[wid][lane + 64] = p1 * inv;

    const unsigned short* Vb = V + (((size_t)b) << 12) * CC;
    float a0 = 0.f, a1 = 0.f, a2 = 0.f, a3 = 0.f;
    for (int i = 0; i < cnt; ++i) {
        float w = s_p[wid][i];
        ushort4 vv = *(const ushort4*)(Vb + (size_t)s_m[wid][i] * CC + lane * 4);
        a0 += w * bf2f(vv.x); a1 += w * bf2f(vv.y);
        a2 += w * bf2f(vv.z); a3 += w * bf2f(vv.w);
    }
    ushort4 o = make_ushort4(f2bf(a0), f2bf(a1), f2bf(a2), f2bf(a3));
    *(ushort4*)(MT + (size_t)bn * CC + lane * 4) = o;
    if (lane == 0) { out1[bn] = ds * inv; out2[bn] = 1.f; }
}

extern "C" void kernel_launch(void* const* d_in, const int* in_sizes, int n_in,
                              void* d_out, int out_size, void* d_ws, size_t ws_size,
                              hipStream_t stream) {
    const float* nodes_L = (const float*)d_in[0];
    const float* nodes_R = (const float*)d_in[1];
    const float* kpts_L  = (const float*)d_in[2];
    const float* kpts_R  = (const float*)d_in[3];
    const float* Wq = (const float*)d_in[4];
    const float* bq = (const float*)d_in[5];
    const float* Wk = (const float*)d_in[6];
    const float* bk = (const float*)d_in[7];
    const float* Wv = (const float*)d_in[8];
    const float* bv = (const float*)d_in[9];
    const float* Wm = (const float*)d_in[10];
    const float* bm = (const float*)d_in[11];

    char* ws = (char*)d_ws;
    unsigned short* Wpk = (unsigned short*)ws; ws += (size_t)4 * 65536 * 2;
    unsigned short* Qp  = (unsigned short*)ws; ws += (size_t)BB * NN * CC * 2;
    unsigned short* Kp  = (unsigned short*)ws; ws += (size_t)BB * MM * CC * 2;
    unsigned short* Vp  = (unsigned short*)ws; ws += (size_t)BB * MM * CC * 2;
    unsigned short* MT  = (unsigned short*)ws; ws += (size_t)BB * NN * CC * 2;
    float* Vsum = (float*)ws;        ws += (size_t)BB * CC * 4;
    float* Usum = (float*)ws;        ws += (size_t)BB * 4;
    float2* sortedUV = (float2*)ws;  ws += (size_t)BB * MM * 8;
    int* binStart = (int*)ws;        ws += (size_t)BB * (NBIN + 1) * 4;
    unsigned short* sortedM = (unsigned short*)ws; ws += (size_t)BB * MM * 2;
    int* hist = (int*)ws;            ws += (size_t)BB * NCH * NBIN * 4;
    int* chunkOff = (int*)ws;        ws += (size_t)BB * NCH * NBIN * 4;
    unsigned short* prank = (unsigned short*)ws;

    float* out0 = (float*)d_out;
    float* out1 = out0 + (size_t)BB * NN * CC;
    float* out2 = out1 + (size_t)BB * NN;

    hipMemsetAsync(Vsum, 0, (size_t)BB * CC * sizeof(float), stream);

    wprep_kernel<<<dim3(256, 4), dim3(256), 0, stream>>>(Wq, Wk, Wv, Wm, Wpk);

    // fused Q/K/V projections (blockIdx.y = 0/1/2), 512 blocks per projection
    proj_mfma_kernel<false, true><<<dim3(512, 3), dim3(256), 0, stream>>>(
        nodes_L, nodes_R, nodes_R, Wpk, bq, bk, bv, Qp, Kp, Vp, Vsum);

    bin_count_kernel<<<dim3(NCH, BB), dim3(256), 0, stream>>>(kpts_R, hist, prank);
    bin_scan_kernel<<<dim3(BB), dim3(NBIN), 0, stream>>>(hist, binStart, chunkOff);
    bin_place_kernel<<<dim3(NCH, BB), dim3(256), 0, stream>>>(
        kpts_R, chunkOff, prank, sortedM, sortedUV);
    urmean_kernel<<<dim3(BB), dim3(256), 0, stream>>>(kpts_R, Usum);

    attn_kernel<<<dim3(BB * NN / 4), dim3(256), 0, stream>>>(
        Qp, Kp, Vp, kpts_L, binStart, sortedM, sortedUV, Vsum, Usum, MT, out1, out2);

    // final projection: out0 = MT @ Wm^T + bm (fp32 out)
    proj_mfma_kernel<true, false><<<dim3(512, 1), dim3(256), 0, stream>>>(
        MT, nullptr, nullptr, Wpk + 3 * 65536, bm, nullptr, nullptr,
        out0, nullptr, nullptr, nullptr);
}

// Round 7
// 93.535 us; speedup vs baseline: 5.2530x; 1.1373x over previous
//
#include <hip/hip_runtime.h>
#include <hip/hip_bf16.h>

#define BB 4
#define NN 4096
#define MM 4096
#define CC 256
#define CAP 128
#define NBIN 384
#define NCH 16
#define CHK 256

typedef __attribute__((ext_vector_type(8))) short bf16x8;
typedef __attribute__((ext_vector_type(4))) float f32x4;

static __device__ __forceinline__ float bf2f(unsigned short u) {
    return __uint_as_float(((unsigned)u) << 16);
}
static __device__ __forceinline__ unsigned short f2bf(float f) {
    unsigned u = __float_as_uint(f);
    u += 0x7fffu + ((u >> 16) & 1u);   // round-to-nearest-even
    return (unsigned short)(u >> 16);
}
static __device__ __forceinline__ bf16x8 asbf(uint4 u) {
    union { uint4 a; bf16x8 b; } c; c.a = u; return c.b;
}

// ---------------- W fp32 -> bf16 packed in MFMA-fragment order + Vsum zero ----
// Wpk[w][kk][t][lane][j] = W[w][t*16 + (lane&15)][kk*32 + (lane>>4)*8 + j]
__global__ void wprep_kernel(const float* __restrict__ Wq, const float* __restrict__ Wk,
                             const float* __restrict__ Wv, const float* __restrict__ Wm,
                             unsigned short* __restrict__ Wpk, float* __restrict__ Vsum) {
    if (blockIdx.y == 0 && blockIdx.x == 0) {
        for (int i = threadIdx.x; i < BB * CC; i += 256) Vsum[i] = 0.f;
    }
    int w = blockIdx.y;
    const float* S = (w == 0) ? Wq : (w == 1) ? Wk : (w == 2) ? Wv : Wm;
    int o = blockIdx.x * 256 + threadIdx.x;      // output element in [0,65536)
    int j = o & 7, lane = (o >> 3) & 63, kt = o >> 9;
    int kk = kt >> 4, t = kt & 15;
    int lrow = lane & 15, lk = lane >> 4;
    int r = t * 16 + lrow, c = kk * 32 + lk * 8 + j;
    Wpk[(size_t)w * 65536 + o] = f2bf(S[r * 256 + c]);
}

// ---------------- A fp32 -> bf16 packed in MFMA-fragment order ----------------
// packed(r,c): po = (r>>4)*4096 + (c>>5)*512 + (((c>>3)&3)*16 + (r&15))*8 + (c&7)
// (so a wave's A-fragment for one 16-row tile, one kk is 1KB contiguous)
__global__ __launch_bounds__(256) void apack_kernel(
    const float* __restrict__ L, const float* __restrict__ R,
    unsigned short* __restrict__ Lpk, unsigned short* __restrict__ Rpk)
{
    __shared__ unsigned short T[64 * 256];       // 32 KB, XOR-swizzled (8-elem granule)
    const float* S = blockIdx.y ? R : L;
    unsigned short* D = blockIdx.y ? Rpk : Lpk;
    const int tid = threadIdx.x, wid = tid >> 6, lane = tid & 63;
    const size_t R0 = (size_t)blockIdx.x * 64;
#pragma unroll
    for (int it = 0; it < 16; ++it) {
        int row = it * 4 + wid;
        float4 f = *(const float4*)(S + (R0 + row) * 256 + lane * 4);
        ushort4 h = make_ushort4(f2bf(f.x), f2bf(f.y), f2bf(f.z), f2bf(f.w));
        int col = lane * 4;
        *(ushort4*)&T[row * 256 + (col ^ ((row & 7) << 3))] = h;
    }
    __syncthreads();
    unsigned short* Dp = D + (size_t)blockIdx.x * 16384;
#pragma unroll
    for (int p = 0; p < 8; ++p) {
        int u = p * 2048 + tid * 8;
        int rt = u >> 12, rem = u & 4095;
        int kk = rem >> 9, ln = (rem >> 3) & 63;
        int row = rt * 16 + (ln & 15);
        int col = kk * 32 + (ln >> 4) * 8;
        *(uint4*)(Dp + u) = *(const uint4*)&T[row * 256 + (col ^ ((row & 7) << 3))];
    }
}

// ---------------- MFMA projection: O = A @ W^T + b (A pre-packed bf16) --------
// wave = 32 rows x 64 cols, block = 128 rows x 64 cols. No LDS / barriers in
// the k-loop: 6 contiguous uint4 loads + 8 MFMA per k-step, reg double-buffer.
// XCD-bijective remap keeps all colgroups of a row-tile on one XCD's L2.
template <bool OUT_BF16>
__global__ __launch_bounds__(256, 4) void proj_mfma_kernel(
    const unsigned short* __restrict__ A0, const unsigned short* __restrict__ A1,
    const unsigned short* __restrict__ A2, const unsigned short* __restrict__ Wpk,
    const float* __restrict__ b0, const float* __restrict__ b1, const float* __restrict__ b2,
    void* __restrict__ O0, void* __restrict__ O1, void* __restrict__ O2,
    float* __restrict__ Vsum)
{
    __shared__ __align__(16) unsigned char BoB[OUT_BF16 ? 16384 : 32768];

    const int tid = threadIdx.x, wid = tid >> 6, lane = tid & 63;
    const int lrow = lane & 15, lk = lane >> 4;
    const int y = blockIdx.y;
    const unsigned short* A = (y == 0) ? A0 : (y == 1) ? A1 : A2;
    const float* bias = (y == 0) ? b0 : (y == 1) ? b1 : b2;
    void* Out = (y == 0) ? O0 : (y == 1) ? O1 : O2;
    const unsigned short* W = Wpk + (size_t)y * 65536;

    const int bid = blockIdx.x;
    const int g = (bid >> 3) & 3;                    // colgroup (64 cols)
    const int rblk = (bid & 7) + ((bid >> 5) << 3);  // [0,128): same rblk -> same XCD
    const size_t rbase = (size_t)rblk * 128;
    const int rt0 = rblk * 8 + wid * 2;

    const unsigned short* Ap = A + (size_t)rt0 * 4096 + lane * 8;
    const unsigned short* Wp = W + g * 2048 + lane * 8;

    f32x4 acc[4][2];
#pragma unroll
    for (int t = 0; t < 4; ++t) {
        acc[t][0] = (f32x4){0.f, 0.f, 0.f, 0.f};
        acc[t][1] = (f32x4){0.f, 0.f, 0.f, 0.f};
    }

    uint4 a[2][2], w[2][4];
    a[0][0] = *(const uint4*)(Ap);
    a[0][1] = *(const uint4*)(Ap + 4096);
#pragma unroll
    for (int t = 0; t < 4; ++t) w[0][t] = *(const uint4*)(Wp + t * 512);

#pragma unroll
    for (int kk = 0; kk < 8; ++kk) {
        const int cur = kk & 1, nxt = cur ^ 1;
        if (kk < 7) {
            a[nxt][0] = *(const uint4*)(Ap + (kk + 1) * 512);
            a[nxt][1] = *(const uint4*)(Ap + 4096 + (kk + 1) * 512);
#pragma unroll
            for (int t = 0; t < 4; ++t)
                w[nxt][t] = *(const uint4*)(Wp + (kk + 1) * 8192 + t * 512);
        }
        bf16x8 af0 = asbf(a[cur][0]);
        bf16x8 af1 = asbf(a[cur][1]);
#pragma unroll
        for (int t = 0; t < 4; ++t) {
            bf16x8 wf = asbf(w[cur][t]);
            acc[t][0] = __builtin_amdgcn_mfma_f32_16x16x32_bf16(af0, wf, acc[t][0], 0, 0, 0);
            acc[t][1] = __builtin_amdgcn_mfma_f32_16x16x32_bf16(af1, wf, acc[t][1], 0, 0, 0);
        }
    }

    // V column sums for the all-masked fallback path (QKV launch, y==2 only)
    if (Vsum != nullptr && y == 2) {
#pragma unroll
        for (int t = 0; t < 4; ++t) {
            int col = g * 64 + t * 16 + lrow;
            float vs = acc[t][0][0] + acc[t][0][1] + acc[t][0][2] + acc[t][0][3]
                     + acc[t][1][0] + acc[t][1][1] + acc[t][1][2] + acc[t][1][3];
            vs += __shfl_xor(vs, 16);
            vs += __shfl_xor(vs, 32);
            if (lk == 0)
                atomicAdd(&Vsum[(rblk >> 5) * CC + col], vs + 32.f * bias[col]);
        }
    }

    if constexpr (OUT_BF16) {
        unsigned short* Bo = (unsigned short*)BoB;   // [128][64]
#pragma unroll
        for (int t = 0; t < 4; ++t) {
            float bb = bias[g * 64 + t * 16 + lrow];
#pragma unroll
            for (int s = 0; s < 2; ++s)
#pragma unroll
                for (int rr = 0; rr < 4; ++rr) {
                    int row = wid * 32 + s * 16 + lk * 4 + rr;
                    Bo[row * 64 + t * 16 + lrow] = f2bf(acc[t][s][rr] + bb);
                }
        }
        __syncthreads();
        unsigned short* O = (unsigned short*)Out;
#pragma unroll
        for (int it = 0; it < 4; ++it) {
            int idx = it * 2048 + tid * 8;
            int row = idx >> 6, col = idx & 63;
            *(uint4*)(O + (rbase + row) * CC + g * 64 + col) = *(const uint4*)&Bo[idx];
        }
    } else {
        float* Bo = (float*)BoB;                     // [128][64]
#pragma unroll
        for (int t = 0; t < 4; ++t) {
            float bb = bias[g * 64 + t * 16 + lrow];
#pragma unroll
            for (int s = 0; s < 2; ++s)
#pragma unroll
                for (int rr = 0; rr < 4; ++rr) {
                    int row = wid * 32 + s * 16 + lk * 4 + rr;
                    Bo[row * 64 + t * 16 + lrow] = acc[t][s][rr] + bb;
                }
        }
        __syncthreads();
        float* O = (float*)Out;
#pragma unroll
        for (int it = 0; it < 8; ++it) {
            int idx = it * 1024 + tid * 4;
            int row = idx >> 6, col = idx & 63;
            *(float4*)(O + (rbase + row) * CC + g * 64 + col) = *(const float4*)&Bo[idx];
        }
    }
}

// ---------------- deterministic chunked counting sort by v-bin ----------------
__global__ __launch_bounds__(256) void bin_count_kernel(
    const float* __restrict__ kptsR, int* __restrict__ hist,
    unsigned short* __restrict__ prank)
{
    __shared__ int h[NBIN];
    __shared__ short sbin[CHK];
    int tid = threadIdx.x, chunk = blockIdx.x, b = blockIdx.y;
    for (int i = tid; i < NBIN; i += CHK) h[i] = 0;
    int m = chunk * CHK + tid;
    float2 p = ((const float2*)kptsR)[(size_t)b * MM + m];
    int bin = (int)p.y;
    sbin[tid] = (short)bin;
    __syncthreads();
    atomicAdd(&h[bin], 1);
    int r = 0;
    for (int t = 0; t < tid; ++t) r += (sbin[t] == bin);
    prank[(b << 12) + m] = (unsigned short)r;
    __syncthreads();
    for (int i = tid; i < NBIN; i += CHK)
        hist[((size_t)b * NCH + chunk) * NBIN + i] = h[i];
}

__global__ __launch_bounds__(NBIN) void bin_scan_kernel(
    const int* __restrict__ hist, int* __restrict__ binStart, int* __restrict__ chunkOff)
{
    __shared__ int sc[NBIN];
    int b = blockIdx.x, v = threadIdx.x;
    int per[NCH];
    int tot = 0;
#pragma unroll
    for (int c = 0; c < NCH; ++c) { per[c] = hist[((size_t)b * NCH + c) * NBIN + v]; tot += per[c]; }
    sc[v] = tot;
    __syncthreads();
    for (int off = 1; off < NBIN; off <<= 1) {
        int t = (v >= off) ? sc[v - off] : 0;
        __syncthreads();
        sc[v] += t;
        __syncthreads();
    }
    int start = v ? sc[v - 1] : 0;
    binStart[b * (NBIN + 1) + v] = start;
    if (v == NBIN - 1) binStart[b * (NBIN + 1) + NBIN] = sc[NBIN - 1];
    int run = start;
#pragma unroll
    for (int c = 0; c < NCH; ++c) {
        chunkOff[((size_t)b * NCH + c) * NBIN + v] = run;
        run += per[c];
    }
}

__global__ __launch_bounds__(256) void bin_place_kernel(
    const float* __restrict__ kptsR, const int* __restrict__ chunkOff,
    const unsigned short* __restrict__ prank,
    unsigned short* __restrict__ sortedM, float2* __restrict__ sortedUV)
{
    int tid = threadIdx.x, chunk = blockIdx.x, b = blockIdx.y;
    int m = chunk * CHK + tid;
    float2 p = ((const float2*)kptsR)[(size_t)b * MM + m];
    int bin = (int)p.y;
    int pos = chunkOff[((size_t)b * NCH + chunk) * NBIN + bin] + prank[(b << 12) + m];
    sortedM[(b << 12) + pos] = (unsigned short)m;
    sortedUV[(b << 12) + pos] = p;
}

// ---------------- mean of u_R per batch ----------------
__global__ __launch_bounds__(256) void urmean_kernel(const float* __restrict__ kptsR,
                                                     float* __restrict__ Usum) {
    int b = blockIdx.x;
    int tid = threadIdx.x;
    float s = 0.f;
    for (int m = tid; m < MM; m += 256) s += kptsR[((size_t)b * MM + m) * 2 + 0];
#pragma unroll
    for (int off = 32; off; off >>= 1) s += __shfl_xor(s, off);
    __shared__ float sr[4];
    int wave = tid >> 6, lane = tid & 63;
    if (lane == 0) sr[wave] = s;
    __syncthreads();
    if (tid == 0) Usum[b] = sr[0] + sr[1] + sr[2] + sr[3];
}

// packed-MT write offset for row bn, cols lane*4..lane*4+3
static __device__ __forceinline__ size_t mt_po(int bn, int lane) {
    return ((size_t)(bn >> 4)) * 4096 + (size_t)(lane >> 3) * 512
         + (size_t)(((lane >> 1) & 3) * 16 + (bn & 15)) * 8 + (lane & 1) * 4;
}

// ---------------- sparse attention: one wave per query row ----------------
__global__ __launch_bounds__(256) void attn_kernel(
    const unsigned short* __restrict__ Q, const unsigned short* __restrict__ K,
    const unsigned short* __restrict__ V,
    const float* __restrict__ kptsL,
    const int* __restrict__ binStart, const unsigned short* __restrict__ sortedM,
    const float2* __restrict__ sortedUV,
    const float* __restrict__ Vsum, const float* __restrict__ Usum,
    unsigned short* __restrict__ Mpk, float* __restrict__ out1, float* __restrict__ out2)
{
    __shared__ unsigned short s_m[4][CAP];
    __shared__ float s_du[4][CAP];
    __shared__ float s_p[4][CAP];

    const int wid = threadIdx.x >> 6, lane = threadIdx.x & 63;
    const int bn = blockIdx.x * 4 + wid;
    const int b = bn >> 12;

    float2 kl = *(const float2*)(kptsL + (size_t)bn * 2);
    float uL = kl.x, vL = kl.y;

    int ifl = (int)vL;
    int v0 = max(0, ifl - 3), v1 = min(NBIN - 1, ifl + 3);
    int s = binStart[b * (NBIN + 1) + v0];
    int e = binStart[b * (NBIN + 1) + v1 + 1];

    int cnt = 0;
    for (int i0 = s; i0 < e; i0 += 64) {
        int i = i0 + lane;
        bool valid = false;
        float du = 0.f;
        int m = 0;
        if (i < e) {
            float2 uv = sortedUV[(b << 12) + i];
            m = sortedM[(b << 12) + i];
            du = uL - uv.x;
            float dv = fabsf(vL - uv.y);
            valid = (dv < 3.0f) && (du > 0.0f) && (du < 192.0f);
        }
        unsigned long long bal = __ballot(valid);
        int pos = cnt + __popcll(bal & ((1ull << lane) - 1ull));
        if (valid && pos < CAP) { s_m[wid][pos] = (unsigned short)m; s_du[wid][pos] = du; }
        cnt += __popcll(bal);
    }
    if (cnt > CAP) cnt = CAP;

    if (cnt == 0) {
        float4 vs = *(const float4*)(Vsum + b * CC + lane * 4);
        ushort4 o = make_ushort4(f2bf(vs.x * (1.f / MM)), f2bf(vs.y * (1.f / MM)),
                                 f2bf(vs.z * (1.f / MM)), f2bf(vs.w * (1.f / MM)));
        *(ushort4*)(Mpk + mt_po(bn, lane)) = o;
        if (lane == 0) { out1[bn] = uL - Usum[b] * (1.f / MM); out2[bn] = 0.f; }
        return;
    }

    ushort4 qu = *(const ushort4*)(Q + (size_t)bn * CC + lane * 4);
    float q0 = bf2f(qu.x), q1 = bf2f(qu.y), q2 = bf2f(qu.z), q3 = bf2f(qu.w);
    const unsigned short* Kb = K + (((size_t)b) << 12) * CC;
    for (int i = 0; i < cnt; ++i) {
        ushort4 kv = *(const ushort4*)(Kb + (size_t)s_m[wid][i] * CC + lane * 4);
        float d = q0 * bf2f(kv.x) + q1 * bf2f(kv.y) + q2 * bf2f(kv.z) + q3 * bf2f(kv.w);
#pragma unroll
        for (int off = 32; off; off >>= 1) d += __shfl_xor(d, off);
        if (lane == 0) s_p[wid][i] = d;
    }

    const float NEG = -3.0e38f;
    float x0 = (lane < cnt) ? s_p[wid][lane] * 0.0625f : NEG;
    float x1 = (lane + 64 < cnt) ? s_p[wid][lane + 64] * 0.0625f : NEG;
    float mx = fmaxf(x0, x1);
#pragma unroll
    for (int off = 32; off; off >>= 1) mx = fmaxf(mx, __shfl_xor(mx, off));
    float p0 = (lane < cnt) ? expf(x0 - mx) : 0.f;
    float p1 = (lane + 64 < cnt) ? expf(x1 - mx) : 0.f;
    float d0 = (lane < cnt) ? s_du[wid][lane] : 0.f;
    float d1 = (lane + 64 < cnt) ? s_du[wid][lane + 64] : 0.f;
    float ps = p0 + p1, ds = p0 * d0 + p1 * d1;
#pragma unroll
    for (int off = 32; off; off >>= 1) { ps += __shfl_xor(ps, off); ds += __shfl_xor(ds, off); }
    float inv = 1.f / ps;
    if (lane < cnt) s_p[wid][lane] = p0 * inv;
    if (lane + 64 < cnt) s_p[wid][lane + 64] = p1 * inv;

    const unsigned short* Vb = V + (((size_t)b) << 12) * CC;
    float a0 = 0.f, a1 = 0.f, a2 = 0.f, a3 = 0.f;
    for (int i = 0; i < cnt; ++i) {
        float w = s_p[wid][i];
        ushort4 vv = *(const ushort4*)(Vb + (size_t)s_m[wid][i] * CC + lane * 4);
        a0 += w * bf2f(vv.x); a1 += w * bf2f(vv.y);
        a2 += w * bf2f(vv.z); a3 += w * bf2f(vv.w);
    }
    ushort4 o = make_ushort4(f2bf(a0), f2bf(a1), f2bf(a2), f2bf(a3));
    *(ushort4*)(Mpk + mt_po(bn, lane)) = o;
    if (lane == 0) { out1[bn] = ds * inv; out2[bn] = 1.f; }
}

extern "C" void kernel_launch(void* const* d_in, const int* in_sizes, int n_in,
                              void* d_out, int out_size, void* d_ws, size_t ws_size,
                              hipStream_t stream) {
    const float* nodes_L = (const float*)d_in[0];
    const float* nodes_R = (const float*)d_in[1];
    const float* kpts_L  = (const float*)d_in[2];
    const float* kpts_R  = (const float*)d_in[3];
    const float* Wq = (const float*)d_in[4];
    const float* bq = (const float*)d_in[5];
    const float* Wk = (const float*)d_in[6];
    const float* bk = (const float*)d_in[7];
    const float* Wv = (const float*)d_in[8];
    const float* bv = (const float*)d_in[9];
    const float* Wm = (const float*)d_in[10];
    const float* bm = (const float*)d_in[11];

    char* ws = (char*)d_ws;
    unsigned short* Wpk = (unsigned short*)ws; ws += (size_t)4 * 65536 * 2;
    unsigned short* Lpk = (unsigned short*)ws; ws += (size_t)BB * NN * CC * 2;
    unsigned short* Rpk = (unsigned short*)ws; ws += (size_t)BB * MM * CC * 2;
    unsigned short* Qp  = (unsigned short*)ws; ws += (size_t)BB * NN * CC * 2;
    unsigned short* Kp  = (unsigned short*)ws; ws += (size_t)BB * MM * CC * 2;
    unsigned short* Vp  = (unsigned short*)ws; ws += (size_t)BB * MM * CC * 2;
    unsigned short* Mpk = (unsigned short*)ws; ws += (size_t)BB * NN * CC * 2;
    float* Vsum = (float*)ws;        ws += (size_t)BB * CC * 4;
    float* Usum = (float*)ws;        ws += (size_t)BB * 4;
    float2* sortedUV = (float2*)ws;  ws += (size_t)BB * MM * 8;
    int* binStart = (int*)ws;        ws += (size_t)BB * (NBIN + 1) * 4;
    unsigned short* sortedM = (unsigned short*)ws; ws += (size_t)BB * MM * 2;
    int* hist = (int*)ws;            ws += (size_t)BB * NCH * NBIN * 4;
    int* chunkOff = (int*)ws;        ws += (size_t)BB * NCH * NBIN * 4;
    unsigned short* prank = (unsigned short*)ws;

    float* out0 = (float*)d_out;
    float* out1 = out0 + (size_t)BB * NN * CC;
    float* out2 = out1 + (size_t)BB * NN;

    wprep_kernel<<<dim3(256, 4), dim3(256), 0, stream>>>(Wq, Wk, Wv, Wm, Wpk, Vsum);
    apack_kernel<<<dim3(256, 2), dim3(256), 0, stream>>>(nodes_L, nodes_R, Lpk, Rpk);

    // fused Q/K/V projections (blockIdx.y = 0/1/2)
    proj_mfma_kernel<true><<<dim3(512, 3), dim3(256), 0, stream>>>(
        Lpk, Rpk, Rpk, Wpk, bq, bk, bv, Qp, Kp, Vp, Vsum);

    bin_count_kernel<<<dim3(NCH, BB), dim3(256), 0, stream>>>(kpts_R, hist, prank);
    bin_scan_kernel<<<dim3(BB), dim3(NBIN), 0, stream>>>(hist, binStart, chunkOff);
    bin_place_kernel<<<dim3(NCH, BB), dim3(256), 0, stream>>>(
        kpts_R, chunkOff, prank, sortedM, sortedUV);
    urmean_kernel<<<dim3(BB), dim3(256), 0, stream>>>(kpts_R, Usum);

    attn_kernel<<<dim3(BB * NN / 4), dim3(256), 0, stream>>>(
        Qp, Kp, Vp, kpts_L, binStart, sortedM, sortedUV, Vsum, Usum, Mpk, out1, out2);

    // final projection: out0 = Mpk @ Wm^T + bm (fp32 out)
    proj_mfma_kernel<false><<<dim3(512, 1), dim3(256), 0, stream>>>(
        Mpk, nullptr, nullptr, Wpk + 3 * 65536, bm, nullptr, nullptr,
        out0, nullptr, nullptr, nullptr);
}

// Round 8
// 66.430 us; speedup vs baseline: 7.3964x; 1.4080x over previous
//
#include <hip/hip_runtime.h>
#include <hip/hip_bf16.h>

#define BB 4
#define NN 4096
#define MM 4096
#define CC 256
#define CAP 128
#define NBIN 384
#define NCH 16
#define CHK 256

typedef __attribute__((ext_vector_type(8))) short bf16x8;
typedef __attribute__((ext_vector_type(4))) float f32x4;

static __device__ __forceinline__ float bf2f(unsigned short u) {
    return __uint_as_float(((unsigned)u) << 16);
}
static __device__ __forceinline__ unsigned short f2bf(float f) {
    unsigned u = __float_as_uint(f);
    u += 0x7fffu + ((u >> 16) & 1u);   // round-to-nearest-even
    return (unsigned short)(u >> 16);
}
static __device__ __forceinline__ bf16x8 asbf(uint4 u) {
    union { uint4 a; bf16x8 b; } c; c.a = u; return c.b;
}
// async global->LDS, 16B per lane; LDS dest wave-uniform base + lane*16B
static __device__ __forceinline__ void gload16(const unsigned short* g, unsigned short* l) {
    __builtin_amdgcn_global_load_lds(
        (const __attribute__((address_space(1))) unsigned int*)g,
        (__attribute__((address_space(3))) unsigned int*)l, 16, 0, 0);
}

// ================= fused prep: wprep / apack / bin_count / urmean / Vsum0 =====
// y 0-3: W fp32->bf16 packed  Wpk[w][kk][t][lane][j] = W[w][t*16+(lane&15)][kk*32+(lane>>4)*8+j]
// y 4-5: A fp32->bf16 packed  po = (r>>4)*4096 + (c>>5)*512 + (((c>>3)&3)*16+(r&15))*8 + (c&7)
// y 6  : per-chunk v-bin histogram + stable rank (x<64)
// y 7  : x<4 urmean(b=x); x==4 Vsum zero
__global__ __launch_bounds__(256) void prep_kernel(
    const float* __restrict__ Wq, const float* __restrict__ Wk,
    const float* __restrict__ Wv, const float* __restrict__ Wm,
    const float* __restrict__ L, const float* __restrict__ R,
    const float* __restrict__ kptsR,
    unsigned short* __restrict__ Wpk, unsigned short* __restrict__ Lpk,
    unsigned short* __restrict__ Rpk,
    int* __restrict__ hist, unsigned short* __restrict__ prank,
    float* __restrict__ Vsum, float* __restrict__ Usum)
{
    __shared__ __align__(16) unsigned char SMEM[32768];
    const int tid = threadIdx.x, y = blockIdx.y, x = blockIdx.x;

    if (y < 4) {                                   // ---- W pack
        const float* S = (y == 0) ? Wq : (y == 1) ? Wk : (y == 2) ? Wv : Wm;
        int o = x * 256 + tid;
        int j = o & 7, lane = (o >> 3) & 63, kt = o >> 9;
        int kk = kt >> 4, t = kt & 15;
        int r = t * 16 + (lane & 15), c = kk * 32 + (lane >> 4) * 8 + j;
        Wpk[(size_t)y * 65536 + o] = f2bf(S[r * 256 + c]);
        return;
    }
    if (y < 6) {                                   // ---- A pack (64 rows/block)
        const float* S = (y == 5) ? R : L;
        unsigned short* D = (y == 5) ? Rpk : Lpk;
        unsigned short* T = (unsigned short*)SMEM;
        const int wid = tid >> 6, lane = tid & 63;
        const size_t R0 = (size_t)x * 64;
#pragma unroll
        for (int it = 0; it < 16; ++it) {
            int row = it * 4 + wid;
            float4 f = *(const float4*)(S + (R0 + row) * 256 + lane * 4);
            ushort4 h = make_ushort4(f2bf(f.x), f2bf(f.y), f2bf(f.z), f2bf(f.w));
            int col = lane * 4;
            *(ushort4*)&T[row * 256 + (col ^ ((row & 7) << 3))] = h;
        }
        __syncthreads();
        unsigned short* Dp = D + (size_t)x * 16384;
#pragma unroll
        for (int p = 0; p < 8; ++p) {
            int u = p * 2048 + tid * 8;
            int rt = u >> 12, rem = u & 4095;
            int kk = rem >> 9, ln = (rem >> 3) & 63;
            int row = rt * 16 + (ln & 15);
            int col = kk * 32 + (ln >> 4) * 8;
            *(uint4*)(Dp + u) = *(const uint4*)&T[row * 256 + (col ^ ((row & 7) << 3))];
        }
        return;
    }
    if (y == 6) {                                  // ---- bin_count
        if (x >= NCH * BB) return;
        int chunk = x & 15, b = x >> 4;
        int* h = (int*)SMEM;
        short* sbin = (short*)(SMEM + NBIN * 4);
        for (int i = tid; i < NBIN; i += CHK) h[i] = 0;
        int m = chunk * CHK + tid;
        float2 p = ((const float2*)kptsR)[(size_t)b * MM + m];
        int bin = (int)p.y;
        sbin[tid] = (short)bin;
        __syncthreads();
        atomicAdd(&h[bin], 1);
        int r = 0;
        for (int t = 0; t < tid; ++t) r += (sbin[t] == bin);
        prank[(b << 12) + m] = (unsigned short)r;
        __syncthreads();
        for (int i = tid; i < NBIN; i += CHK)
            hist[((size_t)b * NCH + chunk) * NBIN + i] = h[i];
        return;
    }
    // ---- y == 7: urmean (x<4) / Vsum zero (x==4)
    if (x < BB) {
        int b = x;
        float s = 0.f;
        for (int m = tid; m < MM; m += 256) s += kptsR[((size_t)b * MM + m) * 2 + 0];
#pragma unroll
        for (int off = 32; off; off >>= 1) s += __shfl_xor(s, off);
        float* sr = (float*)SMEM;
        int wave = tid >> 6, lane = tid & 63;
        if (lane == 0) sr[wave] = s;
        __syncthreads();
        if (tid == 0) Usum[b] = sr[0] + sr[1] + sr[2] + sr[3];
    } else if (x == BB) {
        for (int i = tid; i < BB * CC; i += 256) Vsum[i] = 0.f;
    }
}

// ================= MFMA projection: O = A @ W^T + b (A, W pre-packed bf16) ====
// wave = 32 rows x 64 cols, block = 128 rows x 64 cols. W panel (32KB) staged
// to LDS once via global_load_lds; k-loop = 2 A-loads + 4 ds_read_b128 + 8 MFMA,
// zero barriers. XCD-bijective remap keeps a row-tile's colgroups on one XCD.
// y==3 (QKV launch only): bin_scan service slice (x<4).
template <bool OUT_BF16>
__global__ __launch_bounds__(256, 4) void proj_mfma_kernel(
    const unsigned short* __restrict__ A0, const unsigned short* __restrict__ A1,
    const unsigned short* __restrict__ A2, const unsigned short* __restrict__ Wpk,
    const float* __restrict__ b0, const float* __restrict__ b1, const float* __restrict__ b2,
    void* __restrict__ O0, void* __restrict__ O1, void* __restrict__ O2,
    float* __restrict__ Vsum,
    const int* __restrict__ hist, int* __restrict__ binStart, int* __restrict__ chunkOff)
{
    __shared__ __align__(16) unsigned char SMEM[32768];   // W panel, then bounce/scan
    const int tid = threadIdx.x, wid = tid >> 6, lane = tid & 63;
    const int y = blockIdx.y;

    if (y == 3) {                                  // ---- bin_scan service slice
        if (blockIdx.x >= BB) return;
        int b = blockIdx.x;
        int* sc = (int*)SMEM;
        for (int v = tid; v < NBIN; v += 256) {
            int tot = 0;
            for (int c = 0; c < NCH; ++c) tot += hist[((size_t)b * NCH + c) * NBIN + v];
            sc[v] = tot;
        }
        __syncthreads();
        for (int off = 1; off < NBIN; off <<= 1) {
            int v1 = tid + 256;
            int t0 = (tid >= off) ? sc[tid - off] : 0;
            int t1 = (v1 < NBIN && v1 >= off) ? sc[v1 - off] : 0;
            __syncthreads();
            sc[tid] += t0;
            if (v1 < NBIN) sc[v1] += t1;
            __syncthreads();
        }
        for (int v = tid; v < NBIN; v += 256) {
            int start = v ? sc[v - 1] : 0;
            binStart[b * (NBIN + 1) + v] = start;
            if (v == NBIN - 1) binStart[b * (NBIN + 1) + NBIN] = sc[NBIN - 1];
            int run = start;
            for (int c = 0; c < NCH; ++c) {
                chunkOff[((size_t)b * NCH + c) * NBIN + v] = run;
                run += hist[((size_t)b * NCH + c) * NBIN + v];
            }
        }
        return;
    }

    const int lrow = lane & 15, lk = lane >> 4;
    const unsigned short* A = (y == 0) ? A0 : (y == 1) ? A1 : A2;
    const float* bias = (y == 0) ? b0 : (y == 1) ? b1 : b2;
    void* Out = (y == 0) ? O0 : (y == 1) ? O1 : O2;
    const unsigned short* W = Wpk + (size_t)y * 65536;

    const int bid = blockIdx.x;
    const int g = (bid >> 3) & 3;                    // colgroup (64 cols)
    const int rblk = (bid & 7) + ((bid >> 5) << 3);  // [0,128): same rblk -> same XCD
    const size_t rbase = (size_t)rblk * 128;
    const int rt0 = rblk * 8 + wid * 2;

    // stage this block's W panel (8 kk x 4 t x 1KB = 32KB) into LDS, linear
    unsigned short* Wl = (unsigned short*)SMEM;
#pragma unroll
    for (int i = 0; i < 8; ++i) {
        int kk = wid * 2 + (i >> 2), q = i & 3;
        gload16(W + (size_t)kk * 8192 + g * 2048 + q * 512 + lane * 8,
                Wl + kk * 2048 + q * 512 + lane * 8);
    }

    const unsigned short* Ap = A + (size_t)rt0 * 4096 + lane * 8;
    uint4 a[2][2];
    a[0][0] = *(const uint4*)(Ap);
    a[0][1] = *(const uint4*)(Ap + 4096);

    f32x4 acc[4][2];
#pragma unroll
    for (int t = 0; t < 4; ++t) {
        acc[t][0] = (f32x4){0.f, 0.f, 0.f, 0.f};
        acc[t][1] = (f32x4){0.f, 0.f, 0.f, 0.f};
    }

    asm volatile("s_waitcnt vmcnt(0)" ::: "memory");
    __syncthreads();                                 // W panel resident

#pragma unroll
    for (int kk = 0; kk < 8; ++kk) {
        const int cur = kk & 1, nxt = cur ^ 1;
        if (kk < 7) {
            a[nxt][0] = *(const uint4*)(Ap + (kk + 1) * 512);
            a[nxt][1] = *(const uint4*)(Ap + 4096 + (kk + 1) * 512);
        }
        bf16x8 af0 = asbf(a[cur][0]);
        bf16x8 af1 = asbf(a[cur][1]);
#pragma unroll
        for (int t = 0; t < 4; ++t) {
            bf16x8 wf = *(const bf16x8*)(Wl + kk * 2048 + t * 512 + lane * 8);
            acc[t][0] = __builtin_amdgcn_mfma_f32_16x16x32_bf16(af0, wf, acc[t][0], 0, 0, 0);
            acc[t][1] = __builtin_amdgcn_mfma_f32_16x16x32_bf16(af1, wf, acc[t][1], 0, 0, 0);
        }
    }

    // V column sums for the all-masked fallback path (QKV launch, y==2 only)
    if (Vsum != nullptr && y == 2) {
#pragma unroll
        for (int t = 0; t < 4; ++t) {
            int col = g * 64 + t * 16 + lrow;
            float vs = acc[t][0][0] + acc[t][0][1] + acc[t][0][2] + acc[t][0][3]
                     + acc[t][1][0] + acc[t][1][1] + acc[t][1][2] + acc[t][1][3];
            vs += __shfl_xor(vs, 16);
            vs += __shfl_xor(vs, 32);
            if (lk == 0)
                atomicAdd(&Vsum[(rblk >> 5) * CC + col], vs + 32.f * bias[col]);
        }
    }

    __syncthreads();                                 // done reading Wl; reuse as bounce
    if constexpr (OUT_BF16) {
        unsigned short* Bo = (unsigned short*)SMEM;  // [128][64]
#pragma unroll
        for (int t = 0; t < 4; ++t) {
            float bb = bias[g * 64 + t * 16 + lrow];
#pragma unroll
            for (int s = 0; s < 2; ++s)
#pragma unroll
                for (int rr = 0; rr < 4; ++rr) {
                    int row = wid * 32 + s * 16 + lk * 4 + rr;
                    Bo[row * 64 + t * 16 + lrow] = f2bf(acc[t][s][rr] + bb);
                }
        }
        __syncthreads();
        unsigned short* O = (unsigned short*)Out;
#pragma unroll
        for (int it = 0; it < 4; ++it) {
            int idx = it * 2048 + tid * 8;
            int row = idx >> 6, col = idx & 63;
            *(uint4*)(O + (rbase + row) * CC + g * 64 + col) = *(const uint4*)&Bo[idx];
        }
    } else {
        float* Bo = (float*)SMEM;                    // [128][64]
#pragma unroll
        for (int t = 0; t < 4; ++t) {
            float bb = bias[g * 64 + t * 16 + lrow];
#pragma unroll
            for (int s = 0; s < 2; ++s)
#pragma unroll
                for (int rr = 0; rr < 4; ++rr) {
                    int row = wid * 32 + s * 16 + lk * 4 + rr;
                    Bo[row * 64 + t * 16 + lrow] = acc[t][s][rr] + bb;
                }
        }
        __syncthreads();
        float* O = (float*)Out;
#pragma unroll
        for (int it = 0; it < 8; ++it) {
            int idx = it * 1024 + tid * 4;
            int row = idx >> 6, col = idx & 63;
            *(float4*)(O + (rbase + row) * CC + g * 64 + col) = *(const float4*)&Bo[idx];
        }
    }
}

// ================= scatter into (bin, m)-stable order =========================
__global__ __launch_bounds__(256) void bin_place_kernel(
    const float* __restrict__ kptsR, const int* __restrict__ chunkOff,
    const unsigned short* __restrict__ prank,
    unsigned short* __restrict__ sortedM, float2* __restrict__ sortedUV)
{
    int tid = threadIdx.x, chunk = blockIdx.x, b = blockIdx.y;
    int m = chunk * CHK + tid;
    float2 p = ((const float2*)kptsR)[(size_t)b * MM + m];
    int bin = (int)p.y;
    int pos = chunkOff[((size_t)b * NCH + chunk) * NBIN + bin] + prank[(b << 12) + m];
    sortedM[(b << 12) + pos] = (unsigned short)m;
    sortedUV[(b << 12) + pos] = p;
}

// packed-MT write offset for row bn, cols lane*4..lane*4+3
static __device__ __forceinline__ size_t mt_po(int bn, int lane) {
    return ((size_t)(bn >> 4)) * 4096 + (size_t)(lane >> 3) * 512
         + (size_t)(((lane >> 1) & 3) * 16 + (bn & 15)) * 8 + (lane & 1) * 4;
}

// ================= sparse attention: one wave per query row ===================
__global__ __launch_bounds__(256) void attn_kernel(
    const unsigned short* __restrict__ Q, const unsigned short* __restrict__ K,
    const unsigned short* __restrict__ V,
    const float* __restrict__ kptsL,
    const int* __restrict__ binStart, const unsigned short* __restrict__ sortedM,
    const float2* __restrict__ sortedUV,
    const float* __restrict__ Vsum, const float* __restrict__ Usum,
    unsigned short* __restrict__ Mpk, float* __restrict__ out1, float* __restrict__ out2)
{
    __shared__ unsigned short s_m[4][CAP];
    __shared__ float s_du[4][CAP];
    __shared__ float s_p[4][CAP];

    const int wid = threadIdx.x >> 6, lane = threadIdx.x & 63;
    const int bn = blockIdx.x * 4 + wid;
    const int b = bn >> 12;

    float2 kl = *(const float2*)(kptsL + (size_t)bn * 2);
    float uL = kl.x, vL = kl.y;

    int ifl = (int)vL;
    int v0 = max(0, ifl - 3), v1 = min(NBIN - 1, ifl + 3);
    int s = binStart[b * (NBIN + 1) + v0];
    int e = binStart[b * (NBIN + 1) + v1 + 1];

    int cnt = 0;
    for (int i0 = s; i0 < e; i0 += 64) {
        int i = i0 + lane;
        bool valid = false;
        float du = 0.f;
        int m = 0;
        if (i < e) {
            float2 uv = sortedUV[(b << 12) + i];
            m = sortedM[(b << 12) + i];
            du = uL - uv.x;
            float dv = fabsf(vL - uv.y);
            valid = (dv < 3.0f) && (du > 0.0f) && (du < 192.0f);
        }
        unsigned long long bal = __ballot(valid);
        int pos = cnt + __popcll(bal & ((1ull << lane) - 1ull));
        if (valid && pos < CAP) { s_m[wid][pos] = (unsigned short)m; s_du[wid][pos] = du; }
        cnt += __popcll(bal);
    }
    if (cnt > CAP) cnt = CAP;

    if (cnt == 0) {
        float4 vs = *(const float4*)(Vsum + b * CC + lane * 4);
        ushort4 o = make_ushort4(f2bf(vs.x * (1.f / MM)), f2bf(vs.y * (1.f / MM)),
                                 f2bf(vs.z * (1.f / MM)), f2bf(vs.w * (1.f / MM)));
        *(ushort4*)(Mpk + mt_po(bn, lane)) = o;
        if (lane == 0) { out1[bn] = uL - Usum[b] * (1.f / MM); out2[bn] = 0.f; }
        return;
    }

    // logits: 4 candidates in parallel, one per 16-lane group; lane covers 16 ch
    const int gi = lane >> 4, c = lane & 15;
    float qf[16];
    {
        const unsigned short* Qr = Q + (size_t)bn * CC + c * 16;
#pragma unroll
        for (int j = 0; j < 4; ++j) {
            ushort4 t = *(const ushort4*)(Qr + j * 4);
            qf[j * 4 + 0] = bf2f(t.x); qf[j * 4 + 1] = bf2f(t.y);
            qf[j * 4 + 2] = bf2f(t.z); qf[j * 4 + 3] = bf2f(t.w);
        }
    }
    const unsigned short* Kb = K + (((size_t)b) << 12) * CC;
    for (int i0 = 0; i0 < cnt; i0 += 4) {
        int i = i0 + gi;
        int m = s_m[wid][(i < cnt) ? i : 0];
        const unsigned short* Kr = Kb + (size_t)m * CC + c * 16;
        float d = 0.f;
#pragma unroll
        for (int j = 0; j < 4; ++j) {
            ushort4 t = *(const ushort4*)(Kr + j * 4);
            d += qf[j * 4 + 0] * bf2f(t.x) + qf[j * 4 + 1] * bf2f(t.y)
               + qf[j * 4 + 2] * bf2f(t.z) + qf[j * 4 + 3] * bf2f(t.w);
        }
        d += __shfl_xor(d, 8); d += __shfl_xor(d, 4);
        d += __shfl_xor(d, 2); d += __shfl_xor(d, 1);
        if (c == 0 && i < cnt) s_p[wid][i] = d;
    }

    const float NEG = -3.0e38f;
    float x0 = (lane < cnt) ? s_p[wid][lane] * 0.0625f : NEG;
    float x1 = (lane + 64 < cnt) ? s_p[wid][lane + 64] * 0.0625f : NEG;
    float mx = fmaxf(x0, x1);
#pragma unroll
    for (int off = 32; off; off >>= 1) mx = fmaxf(mx, __shfl_xor(mx, off));
    float p0 = (lane < cnt) ? expf(x0 - mx) : 0.f;
    float p1 = (lane + 64 < cnt) ? expf(x1 - mx) : 0.f;
    float d0 = (lane < cnt) ? s_du[wid][lane] : 0.f;
    float d1 = (lane + 64 < cnt) ? s_du[wid][lane + 64] : 0.f;
    float ps = p0 + p1, ds = p0 * d0 + p1 * d1;
#pragma unroll
    for (int off = 32; off; off >>= 1) { ps += __shfl_xor(ps, off); ds += __shfl_xor(ds, off); }
    float inv = 1.f / ps;
    if (lane < cnt) s_p[wid][lane] = p0 * inv;
    if (lane + 64 < cnt) s_p[wid][lane + 64] = p1 * inv;

    // PV: lane owns 4 output channels; 2-way unrolled accumulators
    const unsigned short* Vb = V + (((size_t)b) << 12) * CC;
    float a0 = 0.f, a1 = 0.f, a2 = 0.f, a3 = 0.f;
    float e0 = 0.f, e1 = 0.f, e2 = 0.f, e3 = 0.f;
    int i = 0;
    for (; i + 1 < cnt; i += 2) {
        float w0 = s_p[wid][i], w1 = s_p[wid][i + 1];
        ushort4 va = *(const ushort4*)(Vb + (size_t)s_m[wid][i] * CC + lane * 4);
        ushort4 vb = *(const ushort4*)(Vb + (size_t)s_m[wid][i + 1] * CC + lane * 4);
        a0 += w0 * bf2f(va.x); a1 += w0 * bf2f(va.y);
        a2 += w0 * bf2f(va.z); a3 += w0 * bf2f(va.w);
        e0 += w1 * bf2f(vb.x); e1 += w1 * bf2f(vb.y);
        e2 += w1 * bf2f(vb.z); e3 += w1 * bf2f(vb.w);
    }
    if (i < cnt) {
        float w0 = s_p[wid][i];
        ushort4 va = *(const ushort4*)(Vb + (size_t)s_m[wid][i] * CC + lane * 4);
        a0 += w0 * bf2f(va.x); a1 += w0 * bf2f(va.y);
        a2 += w0 * bf2f(va.z); a3 += w0 * bf2f(va.w);
    }
    ushort4 o = make_ushort4(f2bf(a0 + e0), f2bf(a1 + e1), f2bf(a2 + e2), f2bf(a3 + e3));
    *(ushort4*)(Mpk + mt_po(bn, lane)) = o;
    if (lane == 0) { out1[bn] = ds * inv; out2[bn] = 1.f; }
}

extern "C" void kernel_launch(void* const* d_in, const int* in_sizes, int n_in,
                              void* d_out, int out_size, void* d_ws, size_t ws_size,
                              hipStream_t stream) {
    const float* nodes_L = (const float*)d_in[0];
    const float* nodes_R = (const float*)d_in[1];
    const float* kpts_L  = (const float*)d_in[2];
    const float* kpts_R  = (const float*)d_in[3];
    const float* Wq = (const float*)d_in[4];
    const float* bq = (const float*)d_in[5];
    const float* Wk = (const float*)d_in[6];
    const float* bk = (const float*)d_in[7];
    const float* Wv = (const float*)d_in[8];
    const float* bv = (const float*)d_in[9];
    const float* Wm = (const float*)d_in[10];
    const float* bm = (const float*)d_in[11];

    char* ws = (char*)d_ws;
    unsigned short* Wpk = (unsigned short*)ws; ws += (size_t)4 * 65536 * 2;
    unsigned short* Lpk = (unsigned short*)ws; ws += (size_t)BB * NN * CC * 2;
    unsigned short* Rpk = (unsigned short*)ws; ws += (size_t)BB * MM * CC * 2;
    unsigned short* Qp  = (unsigned short*)ws; ws += (size_t)BB * NN * CC * 2;
    unsigned short* Kp  = (unsigned short*)ws; ws += (size_t)BB * MM * CC * 2;
    unsigned short* Vp  = (unsigned short*)ws; ws += (size_t)BB * MM * CC * 2;
    unsigned short* Mpk = (unsigned short*)ws; ws += (size_t)BB * NN * CC * 2;
    float* Vsum = (float*)ws;        ws += (size_t)BB * CC * 4;
    float* Usum = (float*)ws;        ws += (size_t)BB * 4;
    float2* sortedUV = (float2*)ws;  ws += (size_t)BB * MM * 8;
    int* binStart = (int*)ws;        ws += (size_t)BB * (NBIN + 1) * 4;
    unsigned short* sortedM = (unsigned short*)ws; ws += (size_t)BB * MM * 2;
    int* hist = (int*)ws;            ws += (size_t)BB * NCH * NBIN * 4;
    int* chunkOff = (int*)ws;        ws += (size_t)BB * NCH * NBIN * 4;
    unsigned short* prank = (unsigned short*)ws;

    float* out0 = (float*)d_out;
    float* out1 = out0 + (size_t)BB * NN * CC;
    float* out2 = out1 + (size_t)BB * NN;

    // 1) fused prep
    prep_kernel<<<dim3(256, 8), dim3(256), 0, stream>>>(
        Wq, Wk, Wv, Wm, nodes_L, nodes_R, kpts_R,
        Wpk, Lpk, Rpk, hist, prank, Vsum, Usum);

    // 2) fused Q/K/V projections (y=0..2) + bin_scan service slice (y=3)
    proj_mfma_kernel<true><<<dim3(512, 4), dim3(256), 0, stream>>>(
        Lpk, Rpk, Rpk, Wpk, bq, bk, bv, Qp, Kp, Vp, Vsum,
        hist, binStart, chunkOff);

    // 3) scatter
    bin_place_kernel<<<dim3(NCH, BB), dim3(256), 0, stream>>>(
        kpts_R, chunkOff, prank, sortedM, sortedUV);

    // 4) sparse attention
    attn_kernel<<<dim3(BB * NN / 4), dim3(256), 0, stream>>>(
        Qp, Kp, Vp, kpts_L, binStart, sortedM, sortedUV, Vsum, Usum, Mpk, out1, out2);

    // 5) final projection: out0 = Mpk @ Wm^T + bm (fp32 out)
    proj_mfma_kernel<false><<<dim3(512, 1), dim3(256), 0, stream>>>(
        Mpk, nullptr, nullptr, Wpk + 3 * 65536, bm, nullptr, nullptr,
        out0, nullptr, nullptr, nullptr, nullptr, nullptr, nullptr);
}